// Round 2
// baseline (898.234 us; speedup 1.0000x reference)
//
#include <hip/hip_runtime.h>
#include <hip/hip_bf16.h>
#include <cstdint>
#include <cstddef>

typedef __bf16 bf16_t;
typedef __bf16 bf16x8 __attribute__((ext_vector_type(8)));
typedef float f32x4 __attribute__((ext_vector_type(4)));

#define B_SZ 32
#define H_SZ 56
#define W_SZ 56
#define N_TOK 3136
#define CH 128
#define M_TOT 100352

enum { A_PLAIN = 0, A_RH_P, A_RW_P, A_RW_M, A_LN, A_BN };
enum { E_BIAS = 0, E_GELU, E_RES };

__device__ __forceinline__ float bf2f(bf16_t v) { return (float)v; }

// ---------------------------------------------------------------------------
// Generic MFMA GEMM: out[M,128] = f(A[M,K]) @ W[K,128] + bias (+epilogue)
// Tile: 64 rows x 128 cols per 256-thread block. K = 128*KHALVES.
// AMODE: fused A-source transform (rolls / LN / BN-ReLU-BN).
// WTRANS=1: W stored [K][128] (fc weights, h @ W). WTRANS=0: W stored [128][K]
// (conv1x1 w[o][c], out = x @ W^T). AF32: A-source is f32 global (else bf16 ws).
// OF32: output f32 (d_out) else bf16 (ws). Weights/bias/params always f32.
// ---------------------------------------------------------------------------
template<int AMODE, int KHALVES, int EPI, int WTRANS, int AF32, int OF32>
__global__ __launch_bounds__(256)
void gemm_k(const void* __restrict__ A0v, const void* __restrict__ A1v,
            const float* __restrict__ Wt, const float* __restrict__ bias,
            const float* __restrict__ resid,
            const float* __restrict__ rowst,
            const float* __restrict__ lnw, const float* __restrict__ lnb,
            const float* __restrict__ bnp,
            void* __restrict__ outv)
{
    __shared__ __align__(16) bf16_t As[64][136];   // +8 pad
    __shared__ __align__(16) bf16_t Bs[128][136];
    const int tid = threadIdx.x;
    const int mbase = blockIdx.x * 64;
    const int lane = tid & 63;
    const int wv = tid >> 6;      // wave 0..3 -> cols [wv*32, wv*32+32)
    const int qd = lane >> 4;     // quad
    const int mr = lane & 15;

    const float* A0f = (const float*)A0v;
    const bf16_t* A0h = (const bf16_t*)A0v;
    const bf16_t* A1h = (const bf16_t*)A1v;

    f32x4 acc[4][2];
#pragma unroll
    for (int i = 0; i < 4; ++i)
#pragma unroll
        for (int j = 0; j < 2; ++j) {
            f32x4 z = {0.f, 0.f, 0.f, 0.f};
            acc[i][j] = z;
        }

    for (int kh = 0; kh < KHALVES; ++kh) {
        if (kh) __syncthreads();
        // ---- stage A tile [64 rows][128 k] ----
        for (int idx = tid; idx < 64 * 16; idx += 256) {
            const int row = idx >> 4;
            const int ck = idx & 15;
            const int rowg = mbase + row;
            if (AMODE == A_PLAIN) {
                if (AF32) {
                    const float* p = A0f + (size_t)rowg * CH + ck * 8;
                    float4 u0 = *(const float4*)p;
                    float4 u1 = *(const float4*)(p + 4);
                    bf16_t t[8] = {(bf16_t)u0.x, (bf16_t)u0.y, (bf16_t)u0.z, (bf16_t)u0.w,
                                   (bf16_t)u1.x, (bf16_t)u1.y, (bf16_t)u1.z, (bf16_t)u1.w};
                    *(uint4*)(&As[row][ck * 8]) = *(const uint4*)t;
                } else {
                    uint4 u = *(const uint4*)(A0h + (size_t)rowg * CH + ck * 8);
                    *(uint4*)(&As[row][ck * 8]) = u;
                }
            } else if (AMODE == A_LN) {
                const bf16_t* src = kh ? A1h : A0h;
                uint4 u = *(const uint4*)(src + (size_t)rowg * CH + ck * 8);
                const bf16_t* up = (const bf16_t*)&u;
                const float mean = rowst[2 * rowg];
                const float rstd = rowst[2 * rowg + 1];
                const int cabs = kh * 128 + ck * 8;
                bf16_t t[8];
#pragma unroll
                for (int j = 0; j < 8; ++j) {
                    float v = (bf2f(up[j]) - mean) * rstd;
                    v = v * lnw[cabs + j] + lnb[cabs + j];
                    t[j] = (bf16_t)v;
                }
                *(uint4*)(&As[row][ck * 8]) = *(const uint4*)t;
            } else if (AMODE == A_BN) {
                if (kh == 0) {
                    uint4 u = *(const uint4*)(A0h + (size_t)rowg * CH + ck * 8);
                    *(uint4*)(&As[row][ck * 8]) = u;
                } else {
                    uint4 u = *(const uint4*)(A1h + (size_t)rowg * CH + ck * 8);
                    const bf16_t* up = (const bf16_t*)&u;
                    bf16_t t[8];
#pragma unroll
                    for (int j = 0; j < 8; ++j) {
                        const int c = ck * 8 + j;
                        float z = fmaxf(0.f, bf2f(up[j]) * bnp[c] + bnp[128 + c]);
                        t[j] = (bf16_t)(z * bnp[256 + c] + bnp[384 + c]);
                    }
                    *(uint4*)(&As[row][ck * 8]) = *(const uint4*)t;
                }
            } else {
                // per-channel rolled gather from x-like [B,N,C]
                const int b = rowg / N_TOK;
                const int n = rowg - b * N_TOK;
                const int h = n / W_SZ;
                const int w = n - h * W_SZ;
                bf16_t t[8];
#pragma unroll
                for (int j = 0; j < 8; ++j) {
                    const int c = ck * 8 + j;
                    int n2;
                    if (AMODE == A_RH_P)      n2 = ((h - c + 224) % 56) * 56 + w; // out[h]=in[(h-c)%56]
                    else if (AMODE == A_RW_P) n2 = h * 56 + ((w - c + 224) % 56); // out[w]=in[(w-c)%56]
                    else                      n2 = h * 56 + ((w + c) % 56);       // out[w]=in[(w+c)%56]
                    const size_t src = ((size_t)b * N_TOK + n2) * CH + c;
                    float v = AF32 ? A0f[src] : bf2f(A0h[src]);
                    t[j] = (bf16_t)v;
                }
                *(uint4*)(&As[row][ck * 8]) = *(const uint4*)t;
            }
        }
        // ---- stage B (f32 weights -> bf16): Bs[n][k] ----
        if (WTRANS) {
            for (int idx = tid; idx < 128 * 16; idx += 256) {
                const int kk = idx >> 4;
                const int cn = idx & 15;
                const float* wp = Wt + (size_t)(kh * 128 + kk) * CH + cn * 8;
                float4 u0 = *(const float4*)wp;
                float4 u1 = *(const float4*)(wp + 4);
                Bs[cn * 8 + 0][kk] = (bf16_t)u0.x;
                Bs[cn * 8 + 1][kk] = (bf16_t)u0.y;
                Bs[cn * 8 + 2][kk] = (bf16_t)u0.z;
                Bs[cn * 8 + 3][kk] = (bf16_t)u0.w;
                Bs[cn * 8 + 4][kk] = (bf16_t)u1.x;
                Bs[cn * 8 + 5][kk] = (bf16_t)u1.y;
                Bs[cn * 8 + 6][kk] = (bf16_t)u1.z;
                Bs[cn * 8 + 7][kk] = (bf16_t)u1.w;
            }
        } else {
            for (int idx = tid; idx < 128 * 16; idx += 256) {
                const int nn = idx >> 4;
                const int ck = idx & 15;
                const float* wp = Wt + (size_t)nn * CH + kh * 128 + ck * 8;
                float4 u0 = *(const float4*)wp;
                float4 u1 = *(const float4*)(wp + 4);
                bf16_t t[8] = {(bf16_t)u0.x, (bf16_t)u0.y, (bf16_t)u0.z, (bf16_t)u0.w,
                               (bf16_t)u1.x, (bf16_t)u1.y, (bf16_t)u1.z, (bf16_t)u1.w};
                *(uint4*)(&Bs[nn][ck * 8]) = *(const uint4*)t;
            }
        }
        __syncthreads();
        // ---- MFMA: 4 k-tiles of 32 ----
#pragma unroll
        for (int kt = 0; kt < 4; ++kt) {
            bf16x8 af[4], bfr[2];
#pragma unroll
            for (int mt = 0; mt < 4; ++mt)
                af[mt] = *(const bf16x8*)(&As[mt * 16 + mr][kt * 32 + qd * 8]);
#pragma unroll
            for (int nt = 0; nt < 2; ++nt)
                bfr[nt] = *(const bf16x8*)(&Bs[wv * 32 + nt * 16 + mr][kt * 32 + qd * 8]);
#pragma unroll
            for (int mt = 0; mt < 4; ++mt)
#pragma unroll
                for (int nt = 0; nt < 2; ++nt)
                    acc[mt][nt] = __builtin_amdgcn_mfma_f32_16x16x32_bf16(
                        af[mt], bfr[nt], acc[mt][nt], 0, 0, 0);
        }
    }
    // ---- epilogue: D row=(qd*4+r), col=lane&15 ----
#pragma unroll
    for (int mt = 0; mt < 4; ++mt) {
#pragma unroll
        for (int nt = 0; nt < 2; ++nt) {
            const int col = wv * 32 + nt * 16 + mr;
            const float bb = bias[col];
#pragma unroll
            for (int r = 0; r < 4; ++r) {
                const int rowg = mbase + mt * 16 + qd * 4 + r;
                float v = acc[mt][nt][r] + bb;
                if (EPI == E_GELU) v = 0.5f * v * (1.f + erff(v * 0.70710678118654752f));
                if (EPI == E_RES)  v += resid[(size_t)rowg * CH + col];
                if (OF32) ((float*)outv)[(size_t)rowg * CH + col] = v;
                else ((bf16_t*)outv)[(size_t)rowg * CH + col] = (bf16_t)v;
            }
        }
    }
}

// ---------------------------------------------------------------------------
// Per-row LN stats over concat [x1p | x2p] (256 bf16 values): wave per row.
// ---------------------------------------------------------------------------
__global__ __launch_bounds__(256)
void rowstats_k(const bf16_t* __restrict__ x1p, const bf16_t* __restrict__ x2p,
                float* __restrict__ rs)
{
    const int row = blockIdx.x * 4 + (threadIdx.x >> 6);
    const int lane = threadIdx.x & 63;
    const bf16_t* p1 = x1p + (size_t)row * CH + lane * 2;
    const bf16_t* p2 = x2p + (size_t)row * CH + lane * 2;
    float a0 = bf2f(p1[0]), a1 = bf2f(p1[1]);
    float b0 = bf2f(p2[0]), b1 = bf2f(p2[1]);
    float s = a0 + a1 + b0 + b1;
    float sq = a0 * a0 + a1 * a1 + b0 * b0 + b1 * b1;
#pragma unroll
    for (int off = 32; off > 0; off >>= 1) {
        s += __shfl_down(s, off);
        sq += __shfl_down(sq, off);
    }
    if (lane == 0) {
        float mean = s * (1.f / 256.f);
        float var = sq * (1.f / 256.f) - mean * mean;
        rs[2 * row] = mean;
        rs[2 * row + 1] = rsqrtf(var + 1e-5f);
    }
}

// ---------------------------------------------------------------------------
// Window attention: one block per 7x7 window (2048 blocks). q/k/v are bf16 ws
// buffers. og may alias qg: all qg reads precede og writes; windows partition
// tokens so no cross-block overlap.
// ---------------------------------------------------------------------------
__global__ __launch_bounds__(256)
void attn_k(const bf16_t* __restrict__ qg, const bf16_t* __restrict__ kg,
            const bf16_t* __restrict__ vg, bf16_t* __restrict__ og)
{
    __shared__ __align__(16) float qs[49][132];
    __shared__ __align__(16) float ks[49][132];
    __shared__ __align__(16) float sc[49][52];
    const int tid = threadIdx.x;
    const int blk = blockIdx.x;
    const int b = blk >> 6;
    const int wy = (blk >> 3) & 7;
    const int wx = blk & 7;

    for (int idx = tid; idx < 49 * 16; idx += 256) {
        const int i = idx >> 4, ck = idx & 15;
        const int n = (wy * 7 + i / 7) * 56 + wx * 7 + (i % 7);
        const size_t off = ((size_t)b * N_TOK + n) * CH + ck * 8;
        uint4 uq = *(const uint4*)(qg + off);
        uint4 uk = *(const uint4*)(kg + off);
        const bf16_t* pq = (const bf16_t*)&uq;
        const bf16_t* pk = (const bf16_t*)&uk;
#pragma unroll
        for (int j = 0; j < 8; ++j) {
            qs[i][ck * 8 + j] = bf2f(pq[j]) * 0.088388347648318447f; // C^-0.5
            ks[i][ck * 8 + j] = bf2f(pk[j]);
        }
    }
    __syncthreads();
    for (int idx = tid; idx < 49 * 49; idx += 256) {
        const int i = idx / 49;
        const int j = idx - i * 49;
        const float4* qp = (const float4*)&qs[i][0];
        const float4* kp = (const float4*)&ks[j][0];
        float s = 0.f;
#pragma unroll 8
        for (int c = 0; c < 32; ++c) {
            float4 a = qp[c], bb = kp[c];
            s += a.x * bb.x + a.y * bb.y + a.z * bb.z + a.w * bb.w;
        }
        sc[i][j] = s;
    }
    __syncthreads();
    if (tid < 49) {
        float mx = -1e30f;
        for (int j = 0; j < 49; ++j) mx = fmaxf(mx, sc[tid][j]);
        float sum = 0.f;
        for (int j = 0; j < 49; ++j) { float e = __expf(sc[tid][j] - mx); sc[tid][j] = e; sum += e; }
        float inv = 1.f / sum;
        for (int j = 0; j < 49; ++j) sc[tid][j] *= inv;
    }
    __syncthreads();
    // stage v into qs (q no longer needed)
    for (int idx = tid; idx < 49 * 16; idx += 256) {
        const int i = idx >> 4, ck = idx & 15;
        const int n = (wy * 7 + i / 7) * 56 + wx * 7 + (i % 7);
        const size_t off = ((size_t)b * N_TOK + n) * CH + ck * 8;
        uint4 uv = *(const uint4*)(vg + off);
        const bf16_t* pv = (const bf16_t*)&uv;
#pragma unroll
        for (int j = 0; j < 8; ++j) qs[i][ck * 8 + j] = bf2f(pv[j]);
    }
    __syncthreads();
    for (int idx = tid; idx < 49 * 128; idx += 256) {
        const int i = idx >> 7, c = idx & 127;
        float s = 0.f;
#pragma unroll 7
        for (int j = 0; j < 49; ++j) s += sc[i][j] * qs[j][c];
        const int n = (wy * 7 + i / 7) * 56 + wx * 7 + (i % 7);
        og[((size_t)b * N_TOK + n) * CH + c] = (bf16_t)s;
    }
}

// ---------------------------------------------------------------------------
// BatchNorm stats (training mode, per channel over B*N rows)
// ---------------------------------------------------------------------------
__global__ __launch_bounds__(256)
void bnstats1_k(const bf16_t* __restrict__ att, float* __restrict__ accum)
{
    __shared__ float ls[256], lq[256];
    const int c = threadIdx.x & 127;
    const int half = threadIdx.x >> 7;
    const size_t rowbase = (size_t)blockIdx.x * 196;
    float s = 0.f, sq = 0.f;
    for (int r = half; r < 196; r += 2) {
        float v = bf2f(att[(rowbase + r) * CH + c]);
        s += v; sq += v * v;
    }
    ls[threadIdx.x] = s; lq[threadIdx.x] = sq;
    __syncthreads();
    if (threadIdx.x < 128) {
        atomicAdd(&accum[c], ls[threadIdx.x] + ls[threadIdx.x + 128]);
        atomicAdd(&accum[128 + c], lq[threadIdx.x] + lq[threadIdx.x + 128]);
    }
}

__global__ __launch_bounds__(256)
void bnstats2_k(const bf16_t* __restrict__ att, const float* __restrict__ g1,
                const float* __restrict__ b1, float* __restrict__ accum)
{
    __shared__ float ls[256], lq[256];
    const int c = threadIdx.x & 127;
    const int half = threadIdx.x >> 7;
    const float m = accum[c] * (1.f / (float)M_TOT);
    const float var = accum[128 + c] * (1.f / (float)M_TOT) - m * m;
    const float rstd = rsqrtf(var + 1e-5f);
    const float scl = g1[c] * rstd;
    const float sh = b1[c] - m * scl;
    const size_t rowbase = (size_t)blockIdx.x * 196;
    float s = 0.f, sq = 0.f;
    for (int r = half; r < 196; r += 2) {
        float z = fmaxf(0.f, bf2f(att[(rowbase + r) * CH + c]) * scl + sh);
        s += z; sq += z * z;
    }
    ls[threadIdx.x] = s; lq[threadIdx.x] = sq;
    __syncthreads();
    if (threadIdx.x < 128) {
        atomicAdd(&accum[256 + c], ls[threadIdx.x] + ls[threadIdx.x + 128]);
        atomicAdd(&accum[384 + c], lq[threadIdx.x] + lq[threadIdx.x + 128]);
    }
}

__global__ void bnparams_k(const float* __restrict__ accum,
                           const float* __restrict__ g1, const float* __restrict__ b1,
                           const float* __restrict__ g2, const float* __restrict__ b2,
                           float* __restrict__ bnp)
{
    const int c = threadIdx.x; // 128 threads
    const float inv = 1.f / (float)M_TOT;
    float m1 = accum[c] * inv;
    float v1 = accum[128 + c] * inv - m1 * m1;
    float rs1 = rsqrtf(v1 + 1e-5f);
    float s1 = g1[c] * rs1;
    float sh1 = b1[c] - m1 * s1;
    float m2 = accum[256 + c] * inv;
    float v2 = accum[384 + c] * inv - m2 * m2;
    float rs2 = rsqrtf(v2 + 1e-5f);
    float s2 = g2[c] * rs2;
    float sh2 = b2[c] - m2 * s2;
    bnp[c] = s1; bnp[128 + c] = sh1; bnp[256 + c] = s2; bnp[384 + c] = sh2;
}

__global__ void zero_k(float* __restrict__ p) { p[threadIdx.x] = 0.f; }

// ---------------------------------------------------------------------------
extern "C" void kernel_launch(void* const* d_in, const int* in_sizes, int n_in,
                              void* d_out, int out_size, void* d_ws, size_t ws_size,
                              hipStream_t stream)
{
    (void)in_sizes; (void)n_in; (void)out_size; (void)ws_size;
    const float* x     = (const float*)d_in[0];
    const float* fc1_w = (const float*)d_in[1];
    const float* fc1_b = (const float*)d_in[2];
    const float* fc2_w = (const float*)d_in[3];
    const float* fc2_b = (const float*)d_in[4];
    const float* fc3_w = (const float*)d_in[5];
    const float* fc3_b = (const float*)d_in[6];
    const float* fc4_w = (const float*)d_in[7];
    const float* fc4_b = (const float*)d_in[8];
    const float* fc5_w = (const float*)d_in[9];
    const float* fc5_b = (const float*)d_in[10];
    const float* fc6_w = (const float*)d_in[11];
    const float* fc6_b = (const float*)d_in[12];
    const float* ln_w  = (const float*)d_in[13];
    const float* ln_b  = (const float*)d_in[14];
    const float* q_w   = (const float*)d_in[15];
    const float* q_b   = (const float*)d_in[16];
    const float* k_w   = (const float*)d_in[17];
    const float* k_b   = (const float*)d_in[18];
    const float* v_w   = (const float*)d_in[19];
    const float* v_b   = (const float*)d_in[20];
    const float* bn1_g = (const float*)d_in[21];
    const float* bn1_b = (const float*)d_in[22];
    const float* bn2_g = (const float*)d_in[23];
    const float* bn2_b = (const float*)d_in[24];

    char* ws = (char*)d_ws;
    const size_t SZB = (size_t)M_TOT * CH * sizeof(bf16_t); // 25.7 MB
    bf16_t* buf0 = (bf16_t*)(ws);
    bf16_t* buf1 = (bf16_t*)(ws + SZB);
    bf16_t* buf2 = (bf16_t*)(ws + 2 * SZB);
    bf16_t* buf3 = (bf16_t*)(ws + 3 * SZB);
    float*  rs   = (float*)(ws + 4 * SZB);
    float*  accum = (float*)(ws + 4 * SZB + (size_t)M_TOT * 2 * sizeof(float));
    float*  bnp  = accum + 512;

    const dim3 blk(256);
    const int GG = M_TOT / 64; // 1568

    zero_k<<<1, 512, 0, stream>>>(accum);

    // branch 1: rollH+ -> fc1+GELU -> rollW+ -> fc2 (+x)  => buf1 = x_1+x
    gemm_k<A_RH_P, 1, E_GELU, 1, 1, 0><<<GG, blk, 0, stream>>>(
        x, nullptr, fc1_w, fc1_b, nullptr, nullptr, nullptr, nullptr, nullptr, buf0);
    gemm_k<A_RW_P, 1, E_RES, 1, 0, 0><<<GG, blk, 0, stream>>>(
        buf0, nullptr, fc2_w, fc2_b, x, nullptr, nullptr, nullptr, nullptr, buf1);
    // branch 2: rollW- -> fc3+GELU -> rollH+ -> fc4 (+x)  => buf2 = x_2+x
    gemm_k<A_RW_M, 1, E_GELU, 1, 1, 0><<<GG, blk, 0, stream>>>(
        x, nullptr, fc3_w, fc3_b, nullptr, nullptr, nullptr, nullptr, nullptr, buf0);
    gemm_k<A_RH_P, 1, E_RES, 1, 0, 0><<<GG, blk, 0, stream>>>(
        buf0, nullptr, fc4_w, fc4_b, x, nullptr, nullptr, nullptr, nullptr, buf2);
    // LN row stats + fc5 (+x) => buf0 = x1
    rowstats_k<<<M_TOT / 4, blk, 0, stream>>>(buf1, buf2, rs);
    gemm_k<A_LN, 2, E_RES, 1, 0, 0><<<GG, blk, 0, stream>>>(
        buf1, buf2, fc5_w, fc5_b, x, rs, ln_w, ln_b, nullptr, buf0);
    // q/k/v 1x1 convs (x f32 -> bf16 ws)
    gemm_k<A_PLAIN, 1, E_BIAS, 0, 1, 0><<<GG, blk, 0, stream>>>(
        x, nullptr, q_w, q_b, nullptr, nullptr, nullptr, nullptr, nullptr, buf1);
    gemm_k<A_PLAIN, 1, E_BIAS, 0, 1, 0><<<GG, blk, 0, stream>>>(
        x, nullptr, k_w, k_b, nullptr, nullptr, nullptr, nullptr, nullptr, buf2);
    gemm_k<A_PLAIN, 1, E_BIAS, 0, 1, 0><<<GG, blk, 0, stream>>>(
        x, nullptr, v_w, v_b, nullptr, nullptr, nullptr, nullptr, nullptr, buf3);
    // window attention => buf1 (overwrites q, safe per-window)
    attn_k<<<B_SZ * 64, blk, 0, stream>>>(buf1, buf2, buf3, buf1);
    // BN stats -> params
    bnstats1_k<<<512, blk, 0, stream>>>(buf1, accum);
    bnstats2_k<<<512, blk, 0, stream>>>(buf1, bn1_g, bn1_b, accum);
    bnparams_k<<<1, 128, 0, stream>>>(accum, bn1_g, bn1_b, bn2_g, bn2_b, bnp);
    // fc6 on [x1 | bn2(relu(bn1(att)))] => d_out (f32)
    gemm_k<A_BN, 2, E_BIAS, 1, 0, 1><<<GG, blk, 0, stream>>>(
        buf0, buf1, fc6_w, fc6_b, nullptr, nullptr, nullptr, nullptr, bnp, d_out);
}

// Round 3
// 720.152 us; speedup vs baseline: 1.2473x; 1.2473x over previous
//
#include <hip/hip_runtime.h>
#include <hip/hip_bf16.h>
#include <cstdint>
#include <cstddef>

typedef __bf16 bf16_t;
typedef __bf16 bf16x8 __attribute__((ext_vector_type(8)));
typedef float f32x4 __attribute__((ext_vector_type(4)));

#define B_SZ 32
#define H_SZ 56
#define W_SZ 56
#define N_TOK 3136
#define CH 128
#define M_TOT 100352

enum { A_FLAT = 0, A_WROLL, A_LN, A_BN };
enum { E_BIAS = 0, E_GELU, E_RES };

__device__ __forceinline__ float bf2f(bf16_t v) { return (float)v; }
__device__ __forceinline__ unsigned short bfbits(float v) {
    bf16_t b = (bf16_t)v; unsigned short u; __builtin_memcpy(&u, &b, 2); return u;
}

// ---------------------------------------------------------------------------
// Transpose: x[B,N,C] f32 -> xT[B,C,N] bf16. 64 tokens per block.
// ---------------------------------------------------------------------------
__global__ __launch_bounds__(256)
void transpose_k(const float* __restrict__ x, bf16_t* __restrict__ xT)
{
    __shared__ bf16_t T[128][70];
    const int tid = threadIdx.x;
    const int mbase = blockIdx.x * 64;
    const int bimg = mbase / N_TOK;
    const int n0 = mbase - bimg * N_TOK;
    for (int idx = tid; idx < 64 * 32; idx += 256) {
        const int tok = idx >> 5, cg = idx & 31;
        float4 u = *(const float4*)(x + (size_t)(mbase + tok) * CH + cg * 4);
        T[cg * 4 + 0][tok] = (bf16_t)u.x;
        T[cg * 4 + 1][tok] = (bf16_t)u.y;
        T[cg * 4 + 2][tok] = (bf16_t)u.z;
        T[cg * 4 + 3][tok] = (bf16_t)u.w;
    }
    __syncthreads();
    const uint* T32 = (const uint*)&T[0][0]; // [128][35]
    for (int idx = tid; idx < 128 * 8; idx += 256) {
        const int c = idx >> 3, chunk = idx & 7;
        uint4 o;
        o.x = T32[c * 35 + chunk * 4 + 0];
        o.y = T32[c * 35 + chunk * 4 + 1];
        o.z = T32[c * 35 + chunk * 4 + 2];
        o.w = T32[c * 35 + chunk * 4 + 3];
        *(uint4*)(xT + ((size_t)(bimg * 128 + c)) * N_TOK + n0 + chunk * 8) = o;
    }
}

// ---------------------------------------------------------------------------
// MFMA GEMM: out[M,128] = f(A) @ W[K,128] + bias (+epilogue). 64x128 tile.
// A_FLAT : A from [C,N] bf16, token shift n2=(n-56c) mod 3136 (H-roll +c)
// A_WROLL: A from [C,N] bf16, w' = (w + WDIR*c) mod 56
// A_LN   : A = LN(concat) from two [N,C] bf16 buffers (KHALVES=2)
// A_BN   : A = [x1 | bn2(relu(bn1(att)))] (KHALVES=2)
// OTRANS : write output (after EPI) transposed to [C,N] bf16 via LDS restage
// OF32   : f32 output (d_out). resid is f32 (the original x).
// ---------------------------------------------------------------------------
template<int AMODE, int KHALVES, int EPI, int WDIR, int OTRANS, int OF32>
__global__ __launch_bounds__(256)
void gemm_k(const bf16_t* __restrict__ A0, const bf16_t* __restrict__ A1,
            const float* __restrict__ Wt, const float* __restrict__ bias,
            const float* __restrict__ resid,
            const float* __restrict__ rowst,
            const float* __restrict__ lnw, const float* __restrict__ lnb,
            const float* __restrict__ bnp,
            void* __restrict__ outv)
{
    __shared__ __align__(16) bf16_t As[64][136];
    __shared__ __align__(16) bf16_t Bs[128][136];
    const int tid = threadIdx.x;
    const int mbase = blockIdx.x * 64;
    const int bimg = mbase / N_TOK;
    const int n0 = mbase - bimg * N_TOK;
    const int lane = tid & 63;
    const int wv = tid >> 6;
    const int qd = lane >> 4;
    const int mr = lane & 15;

    f32x4 acc[4][2];
#pragma unroll
    for (int i = 0; i < 4; ++i)
#pragma unroll
        for (int j = 0; j < 2; ++j) { f32x4 z = {0.f,0.f,0.f,0.f}; acc[i][j] = z; }

    for (int kh = 0; kh < KHALVES; ++kh) {
        if (kh) __syncthreads();
        // ---- stage A tile ----
        if (AMODE == A_FLAT || AMODE == A_WROLL) {
            for (int idx = tid; idx < 128 * 8; idx += 256) {
                const int c = idx >> 3, chunk = idx & 7;
                const int cm = (c >= 112) ? c - 112 : (c >= 56 ? c - 56 : c);
                const bf16_t* crow = A0 + ((size_t)(bimg * 128 + c)) * N_TOK;
                if (AMODE == A_FLAT) {
                    int t = n0 + chunk * 8 + N_TOK - 56 * cm;
                    if (t >= N_TOK) t -= N_TOK;
                    uint4 u = *(const uint4*)(crow + t);
                    const bf16_t* up = (const bf16_t*)&u;
#pragma unroll
                    for (int j = 0; j < 8; ++j) As[chunk * 8 + j][c] = up[j];
                } else {
                    const int nl = n0 + chunk * 8;
                    const int h = nl / 56;
                    const int w0 = nl - h * 56;
                    int ws = (WDIR > 0) ? (w0 + cm) : (w0 + 56 - cm);
                    if (ws >= 56) ws -= 56;
                    const bf16_t* hrow = crow + h * 56;
                    if (ws <= 48) {
                        uint4 u = *(const uint4*)(hrow + ws);
                        const bf16_t* up = (const bf16_t*)&u;
#pragma unroll
                        for (int j = 0; j < 8; ++j) As[chunk * 8 + j][c] = up[j];
                    } else {
#pragma unroll
                        for (int j = 0; j < 8; ++j) {
                            int wj = ws + j; if (wj >= 56) wj -= 56;
                            As[chunk * 8 + j][c] = hrow[wj];
                        }
                    }
                }
            }
        } else if (AMODE == A_LN) {
            for (int idx = tid; idx < 64 * 16; idx += 256) {
                const int row = idx >> 4, ck = idx & 15;
                const int rowg = mbase + row;
                const bf16_t* src = kh ? A1 : A0;
                uint4 u = *(const uint4*)(src + (size_t)rowg * CH + ck * 8);
                const bf16_t* up = (const bf16_t*)&u;
                const float mean = rowst[2 * rowg];
                const float rstd = rowst[2 * rowg + 1];
                const int cabs = kh * 128 + ck * 8;
                bf16_t t[8];
#pragma unroll
                for (int j = 0; j < 8; ++j) {
                    float v = (bf2f(up[j]) - mean) * rstd;
                    v = v * lnw[cabs + j] + lnb[cabs + j];
                    t[j] = (bf16_t)v;
                }
                *(uint4*)(&As[row][ck * 8]) = *(const uint4*)t;
            }
        } else { // A_BN
            for (int idx = tid; idx < 64 * 16; idx += 256) {
                const int row = idx >> 4, ck = idx & 15;
                const int rowg = mbase + row;
                if (kh == 0) {
                    uint4 u = *(const uint4*)(A0 + (size_t)rowg * CH + ck * 8);
                    *(uint4*)(&As[row][ck * 8]) = u;
                } else {
                    uint4 u = *(const uint4*)(A1 + (size_t)rowg * CH + ck * 8);
                    const bf16_t* up = (const bf16_t*)&u;
                    bf16_t t[8];
#pragma unroll
                    for (int j = 0; j < 8; ++j) {
                        const int c = ck * 8 + j;
                        float z = fmaxf(0.f, bf2f(up[j]) * bnp[c] + bnp[128 + c]);
                        t[j] = (bf16_t)(z * bnp[256 + c] + bnp[384 + c]);
                    }
                    *(uint4*)(&As[row][ck * 8]) = *(const uint4*)t;
                }
            }
        }
        // ---- stage B: Bs[n][k] from f32 W[K][128] ----
        for (int idx = tid; idx < 128 * 16; idx += 256) {
            const int kk = idx >> 4, cn = idx & 15;
            const float* wp = Wt + (size_t)(kh * 128 + kk) * CH + cn * 8;
            float4 u0 = *(const float4*)wp;
            float4 u1 = *(const float4*)(wp + 4);
            Bs[cn * 8 + 0][kk] = (bf16_t)u0.x;
            Bs[cn * 8 + 1][kk] = (bf16_t)u0.y;
            Bs[cn * 8 + 2][kk] = (bf16_t)u0.z;
            Bs[cn * 8 + 3][kk] = (bf16_t)u0.w;
            Bs[cn * 8 + 4][kk] = (bf16_t)u1.x;
            Bs[cn * 8 + 5][kk] = (bf16_t)u1.y;
            Bs[cn * 8 + 6][kk] = (bf16_t)u1.z;
            Bs[cn * 8 + 7][kk] = (bf16_t)u1.w;
        }
        __syncthreads();
#pragma unroll
        for (int kt = 0; kt < 4; ++kt) {
            bf16x8 af[4], bfr[2];
#pragma unroll
            for (int mt = 0; mt < 4; ++mt)
                af[mt] = *(const bf16x8*)(&As[mt * 16 + mr][kt * 32 + qd * 8]);
#pragma unroll
            for (int nt = 0; nt < 2; ++nt)
                bfr[nt] = *(const bf16x8*)(&Bs[wv * 32 + nt * 16 + mr][kt * 32 + qd * 8]);
#pragma unroll
            for (int mt = 0; mt < 4; ++mt)
#pragma unroll
                for (int nt = 0; nt < 2; ++nt)
                    acc[mt][nt] = __builtin_amdgcn_mfma_f32_16x16x32_bf16(
                        af[mt], bfr[nt], acc[mt][nt], 0, 0, 0);
        }
    }
    // ---- epilogue ----
    if (OTRANS) {
        __syncthreads();               // all Bs reads complete
        uint* T32 = (uint*)&Bs[0][0];  // bf16 [128][70] as uint [128][35]
#pragma unroll
        for (int mt = 0; mt < 4; ++mt)
#pragma unroll
            for (int nt = 0; nt < 2; ++nt) {
                const int col = wv * 32 + nt * 16 + mr;
                const float bb = bias[col];
#pragma unroll
                for (int rp = 0; rp < 2; ++rp) {
                    float v0 = acc[mt][nt][2 * rp] + bb;
                    float v1 = acc[mt][nt][2 * rp + 1] + bb;
                    if (EPI == E_GELU) {
                        v0 = 0.5f * v0 * (1.f + erff(v0 * 0.70710678118654752f));
                        v1 = 0.5f * v1 * (1.f + erff(v1 * 0.70710678118654752f));
                    }
                    T32[col * 35 + mt * 8 + qd * 2 + rp] =
                        (uint)bfbits(v0) | ((uint)bfbits(v1) << 16);
                }
            }
        __syncthreads();
        const int c = tid >> 1, half = tid & 1;
        uint r[16];
#pragma unroll
        for (int j = 0; j < 16; ++j) r[j] = T32[c * 35 + half * 16 + j];
        bf16_t* op = (bf16_t*)outv + ((size_t)(bimg * 128 + c)) * N_TOK + n0 + half * 32;
        uint4 o0 = {r[0], r[1], r[2], r[3]};
        uint4 o1 = {r[4], r[5], r[6], r[7]};
        uint4 o2 = {r[8], r[9], r[10], r[11]};
        uint4 o3 = {r[12], r[13], r[14], r[15]};
        ((uint4*)op)[0] = o0; ((uint4*)op)[1] = o1;
        ((uint4*)op)[2] = o2; ((uint4*)op)[3] = o3;
    } else {
#pragma unroll
        for (int mt = 0; mt < 4; ++mt)
#pragma unroll
            for (int nt = 0; nt < 2; ++nt) {
                const int col = wv * 32 + nt * 16 + mr;
                const float bb = bias[col];
#pragma unroll
                for (int r = 0; r < 4; ++r) {
                    const int rowg = mbase + mt * 16 + qd * 4 + r;
                    float v = acc[mt][nt][r] + bb;
                    if (EPI == E_GELU) v = 0.5f * v * (1.f + erff(v * 0.70710678118654752f));
                    if (EPI == E_RES)  v += resid[(size_t)rowg * CH + col];
                    if (OF32) ((float*)outv)[(size_t)rowg * CH + col] = v;
                    else ((bf16_t*)outv)[(size_t)rowg * CH + col] = (bf16_t)v;
                }
            }
    }
}

// ---------------------------------------------------------------------------
// Fused q/k/v: stage x-tile (f32->bf16) once, loop 3 conv weights [128][128].
// ---------------------------------------------------------------------------
__global__ __launch_bounds__(256)
void qkv_k(const float* __restrict__ x,
           const float* __restrict__ qw, const float* __restrict__ qb,
           const float* __restrict__ kw, const float* __restrict__ kb,
           const float* __restrict__ vw, const float* __restrict__ vb,
           bf16_t* __restrict__ qo, bf16_t* __restrict__ ko, bf16_t* __restrict__ vo)
{
    __shared__ __align__(16) bf16_t As[64][136];
    __shared__ __align__(16) bf16_t Bs[128][136];
    const int tid = threadIdx.x;
    const int mbase = blockIdx.x * 64;
    const int lane = tid & 63;
    const int wv = tid >> 6;
    const int qd = lane >> 4;
    const int mr = lane & 15;

    for (int idx = tid; idx < 64 * 16; idx += 256) {
        const int row = idx >> 4, ck = idx & 15;
        const float* p = x + (size_t)(mbase + row) * CH + ck * 8;
        float4 u0 = *(const float4*)p;
        float4 u1 = *(const float4*)(p + 4);
        bf16_t t[8] = {(bf16_t)u0.x, (bf16_t)u0.y, (bf16_t)u0.z, (bf16_t)u0.w,
                       (bf16_t)u1.x, (bf16_t)u1.y, (bf16_t)u1.z, (bf16_t)u1.w};
        *(uint4*)(&As[row][ck * 8]) = *(const uint4*)t;
    }
    const float* ws3[3] = {qw, kw, vw};
    const float* bs3[3] = {qb, kb, vb};
    bf16_t* os3[3] = {qo, ko, vo};
    for (int s = 0; s < 3; ++s) {
        __syncthreads(); // As ready / prior MFMA Bs-reads done
        for (int idx = tid; idx < 128 * 16; idx += 256) {
            const int nn = idx >> 4, ck = idx & 15;
            const float* wp = ws3[s] + (size_t)nn * CH + ck * 8;
            float4 u0 = *(const float4*)wp;
            float4 u1 = *(const float4*)(wp + 4);
            bf16_t t[8] = {(bf16_t)u0.x, (bf16_t)u0.y, (bf16_t)u0.z, (bf16_t)u0.w,
                           (bf16_t)u1.x, (bf16_t)u1.y, (bf16_t)u1.z, (bf16_t)u1.w};
            *(uint4*)(&Bs[nn][ck * 8]) = *(const uint4*)t;
        }
        __syncthreads();
        f32x4 acc[4][2];
#pragma unroll
        for (int i = 0; i < 4; ++i)
#pragma unroll
            for (int j = 0; j < 2; ++j) { f32x4 z = {0.f,0.f,0.f,0.f}; acc[i][j] = z; }
#pragma unroll
        for (int kt = 0; kt < 4; ++kt) {
            bf16x8 af[4], bfr[2];
#pragma unroll
            for (int mt = 0; mt < 4; ++mt)
                af[mt] = *(const bf16x8*)(&As[mt * 16 + mr][kt * 32 + qd * 8]);
#pragma unroll
            for (int nt = 0; nt < 2; ++nt)
                bfr[nt] = *(const bf16x8*)(&Bs[wv * 32 + nt * 16 + mr][kt * 32 + qd * 8]);
#pragma unroll
            for (int mt = 0; mt < 4; ++mt)
#pragma unroll
                for (int nt = 0; nt < 2; ++nt)
                    acc[mt][nt] = __builtin_amdgcn_mfma_f32_16x16x32_bf16(
                        af[mt], bfr[nt], acc[mt][nt], 0, 0, 0);
        }
        bf16_t* out = os3[s];
#pragma unroll
        for (int mt = 0; mt < 4; ++mt)
#pragma unroll
            for (int nt = 0; nt < 2; ++nt) {
                const int col = wv * 32 + nt * 16 + mr;
                const float bb = bs3[s][col];
#pragma unroll
                for (int r = 0; r < 4; ++r) {
                    const int rowg = mbase + mt * 16 + qd * 4 + r;
                    out[(size_t)rowg * CH + col] = (bf16_t)(acc[mt][nt][r] + bb);
                }
            }
    }
}

// ---------------------------------------------------------------------------
__global__ __launch_bounds__(256)
void rowstats_k(const bf16_t* __restrict__ x1p, const bf16_t* __restrict__ x2p,
                float* __restrict__ rs)
{
    const int row = blockIdx.x * 4 + (threadIdx.x >> 6);
    const int lane = threadIdx.x & 63;
    const bf16_t* p1 = x1p + (size_t)row * CH + lane * 2;
    const bf16_t* p2 = x2p + (size_t)row * CH + lane * 2;
    float a0 = bf2f(p1[0]), a1 = bf2f(p1[1]);
    float b0 = bf2f(p2[0]), b1 = bf2f(p2[1]);
    float s = a0 + a1 + b0 + b1;
    float sq = a0 * a0 + a1 * a1 + b0 * b0 + b1 * b1;
#pragma unroll
    for (int off = 32; off > 0; off >>= 1) {
        s += __shfl_down(s, off);
        sq += __shfl_down(sq, off);
    }
    if (lane == 0) {
        float mean = s * (1.f / 256.f);
        float var = sq * (1.f / 256.f) - mean * mean;
        rs[2 * row] = mean;
        rs[2 * row + 1] = rsqrtf(var + 1e-5f);
    }
}

// ---------------------------------------------------------------------------
__global__ __launch_bounds__(256)
void attn_k(const bf16_t* __restrict__ qg, const bf16_t* __restrict__ kg,
            const bf16_t* __restrict__ vg, bf16_t* __restrict__ og)
{
    __shared__ __align__(16) float qs[49][132];
    __shared__ __align__(16) float ks[49][132];
    __shared__ __align__(16) float sc[49][52];
    const int tid = threadIdx.x;
    const int blk = blockIdx.x;
    const int b = blk >> 6;
    const int wy = (blk >> 3) & 7;
    const int wx = blk & 7;

    for (int idx = tid; idx < 49 * 16; idx += 256) {
        const int i = idx >> 4, ck = idx & 15;
        const int n = (wy * 7 + i / 7) * 56 + wx * 7 + (i % 7);
        const size_t off = ((size_t)b * N_TOK + n) * CH + ck * 8;
        uint4 uq = *(const uint4*)(qg + off);
        uint4 uk = *(const uint4*)(kg + off);
        const bf16_t* pq = (const bf16_t*)&uq;
        const bf16_t* pk = (const bf16_t*)&uk;
#pragma unroll
        for (int j = 0; j < 8; ++j) {
            qs[i][ck * 8 + j] = bf2f(pq[j]) * 0.088388347648318447f;
            ks[i][ck * 8 + j] = bf2f(pk[j]);
        }
    }
    __syncthreads();
    for (int idx = tid; idx < 49 * 49; idx += 256) {
        const int i = idx / 49;
        const int j = idx - i * 49;
        const float4* qp = (const float4*)&qs[i][0];
        const float4* kp = (const float4*)&ks[j][0];
        float s = 0.f;
#pragma unroll 8
        for (int c = 0; c < 32; ++c) {
            float4 a = qp[c], bb = kp[c];
            s += a.x * bb.x + a.y * bb.y + a.z * bb.z + a.w * bb.w;
        }
        sc[i][j] = s;
    }
    __syncthreads();
    if (tid < 49) {
        float mx = -1e30f;
        for (int j = 0; j < 49; ++j) mx = fmaxf(mx, sc[tid][j]);
        float sum = 0.f;
        for (int j = 0; j < 49; ++j) { float e = __expf(sc[tid][j] - mx); sc[tid][j] = e; sum += e; }
        float inv = 1.f / sum;
        for (int j = 0; j < 49; ++j) sc[tid][j] *= inv;
    }
    __syncthreads();
    for (int idx = tid; idx < 49 * 16; idx += 256) {
        const int i = idx >> 4, ck = idx & 15;
        const int n = (wy * 7 + i / 7) * 56 + wx * 7 + (i % 7);
        const size_t off = ((size_t)b * N_TOK + n) * CH + ck * 8;
        uint4 uv = *(const uint4*)(vg + off);
        const bf16_t* pv = (const bf16_t*)&uv;
#pragma unroll
        for (int j = 0; j < 8; ++j) qs[i][ck * 8 + j] = bf2f(pv[j]);
    }
    __syncthreads();
    for (int idx = tid; idx < 49 * 128; idx += 256) {
        const int i = idx >> 7, c = idx & 127;
        float s = 0.f;
#pragma unroll 7
        for (int j = 0; j < 49; ++j) s += sc[i][j] * qs[j][c];
        const int n = (wy * 7 + i / 7) * 56 + wx * 7 + (i % 7);
        og[((size_t)b * N_TOK + n) * CH + c] = (bf16_t)s;
    }
}

// ---------------------------------------------------------------------------
__global__ __launch_bounds__(256)
void bnstats1_k(const bf16_t* __restrict__ att, float* __restrict__ accum)
{
    __shared__ float ls[256], lq[256];
    const int c = threadIdx.x & 127;
    const int half = threadIdx.x >> 7;
    const size_t rowbase = (size_t)blockIdx.x * 196;
    float s = 0.f, sq = 0.f;
    for (int r = half; r < 196; r += 2) {
        float v = bf2f(att[(rowbase + r) * CH + c]);
        s += v; sq += v * v;
    }
    ls[threadIdx.x] = s; lq[threadIdx.x] = sq;
    __syncthreads();
    if (threadIdx.x < 128) {
        atomicAdd(&accum[c], ls[threadIdx.x] + ls[threadIdx.x + 128]);
        atomicAdd(&accum[128 + c], lq[threadIdx.x] + lq[threadIdx.x + 128]);
    }
}

__global__ __launch_bounds__(256)
void bnstats2_k(const bf16_t* __restrict__ att, const float* __restrict__ g1,
                const float* __restrict__ b1, float* __restrict__ accum)
{
    __shared__ float ls[256], lq[256];
    const int c = threadIdx.x & 127;
    const int half = threadIdx.x >> 7;
    const float m = accum[c] * (1.f / (float)M_TOT);
    const float var = accum[128 + c] * (1.f / (float)M_TOT) - m * m;
    const float rstd = rsqrtf(var + 1e-5f);
    const float scl = g1[c] * rstd;
    const float sh = b1[c] - m * scl;
    const size_t rowbase = (size_t)blockIdx.x * 196;
    float s = 0.f, sq = 0.f;
    for (int r = half; r < 196; r += 2) {
        float z = fmaxf(0.f, bf2f(att[(rowbase + r) * CH + c]) * scl + sh);
        s += z; sq += z * z;
    }
    ls[threadIdx.x] = s; lq[threadIdx.x] = sq;
    __syncthreads();
    if (threadIdx.x < 128) {
        atomicAdd(&accum[256 + c], ls[threadIdx.x] + ls[threadIdx.x + 128]);
        atomicAdd(&accum[384 + c], lq[threadIdx.x] + lq[threadIdx.x + 128]);
    }
}

__global__ void bnparams_k(const float* __restrict__ accum,
                           const float* __restrict__ g1, const float* __restrict__ b1,
                           const float* __restrict__ g2, const float* __restrict__ b2,
                           float* __restrict__ bnp)
{
    const int c = threadIdx.x;
    const float inv = 1.f / (float)M_TOT;
    float m1 = accum[c] * inv;
    float v1 = accum[128 + c] * inv - m1 * m1;
    float rs1 = rsqrtf(v1 + 1e-5f);
    float s1 = g1[c] * rs1;
    float sh1 = b1[c] - m1 * s1;
    float m2 = accum[256 + c] * inv;
    float v2 = accum[384 + c] * inv - m2 * m2;
    float rs2 = rsqrtf(v2 + 1e-5f);
    float s2 = g2[c] * rs2;
    float sh2 = b2[c] - m2 * s2;
    bnp[c] = s1; bnp[128 + c] = sh1; bnp[256 + c] = s2; bnp[384 + c] = sh2;
}

__global__ void zero_k(float* __restrict__ p) { p[threadIdx.x] = 0.f; }

// ---------------------------------------------------------------------------
extern "C" void kernel_launch(void* const* d_in, const int* in_sizes, int n_in,
                              void* d_out, int out_size, void* d_ws, size_t ws_size,
                              hipStream_t stream)
{
    (void)in_sizes; (void)n_in; (void)out_size; (void)ws_size;
    const float* x     = (const float*)d_in[0];
    const float* fc1_w = (const float*)d_in[1];
    const float* fc1_b = (const float*)d_in[2];
    const float* fc2_w = (const float*)d_in[3];
    const float* fc2_b = (const float*)d_in[4];
    const float* fc3_w = (const float*)d_in[5];
    const float* fc3_b = (const float*)d_in[6];
    const float* fc4_w = (const float*)d_in[7];
    const float* fc4_b = (const float*)d_in[8];
    const float* fc5_w = (const float*)d_in[9];
    const float* fc5_b = (const float*)d_in[10];
    const float* fc6_w = (const float*)d_in[11];
    const float* fc6_b = (const float*)d_in[12];
    const float* ln_w  = (const float*)d_in[13];
    const float* ln_b  = (const float*)d_in[14];
    const float* q_w   = (const float*)d_in[15];
    const float* q_b   = (const float*)d_in[16];
    const float* k_w   = (const float*)d_in[17];
    const float* k_b   = (const float*)d_in[18];
    const float* v_w   = (const float*)d_in[19];
    const float* v_b   = (const float*)d_in[20];
    const float* bn1_g = (const float*)d_in[21];
    const float* bn1_b = (const float*)d_in[22];
    const float* bn2_g = (const float*)d_in[23];
    const float* bn2_b = (const float*)d_in[24];

    char* ws = (char*)d_ws;
    const size_t SZB = (size_t)M_TOT * CH * sizeof(bf16_t); // 25.7 MB
    bf16_t* bufA = (bf16_t*)(ws);            // xT -> q -> attn out
    bf16_t* bufB = (bf16_t*)(ws + SZB);      // y1T -> y3T -> x1
    bf16_t* bufC = (bf16_t*)(ws + 2 * SZB);  // x_1+x -> k
    bf16_t* bufD = (bf16_t*)(ws + 3 * SZB);  // x_2+x -> v
    float*  rs   = (float*)(ws + 4 * SZB);
    float*  accum = (float*)(ws + 4 * SZB + (size_t)M_TOT * 2 * sizeof(float));
    float*  bnp  = accum + 512;

    const dim3 blk(256);
    const int GG = M_TOT / 64; // 1568

    zero_k<<<1, 512, 0, stream>>>(accum);
    transpose_k<<<GG, blk, 0, stream>>>(x, bufA);
    // branch 1: fc1 (H-roll +c) + GELU -> y1T [C,N]
    gemm_k<A_FLAT, 1, E_GELU, 0, 1, 0><<<GG, blk, 0, stream>>>(
        bufA, nullptr, fc1_w, fc1_b, nullptr, nullptr, nullptr, nullptr, nullptr, bufB);
    // fc2 (W-roll +c on y1T) + x -> bufC [N,C]
    gemm_k<A_WROLL, 1, E_RES, -1, 0, 0><<<GG, blk, 0, stream>>>(
        bufB, nullptr, fc2_w, fc2_b, x, nullptr, nullptr, nullptr, nullptr, bufC);
    // branch 2: fc3 (W-roll -c) + GELU -> y3T [C,N]
    gemm_k<A_WROLL, 1, E_GELU, 1, 1, 0><<<GG, blk, 0, stream>>>(
        bufA, nullptr, fc3_w, fc3_b, nullptr, nullptr, nullptr, nullptr, nullptr, bufB);
    // fc4 (H-roll +c on y3T) + x -> bufD [N,C]
    gemm_k<A_FLAT, 1, E_RES, 0, 0, 0><<<GG, blk, 0, stream>>>(
        bufB, nullptr, fc4_w, fc4_b, x, nullptr, nullptr, nullptr, nullptr, bufD);
    // LN stats + fc5 (+x) -> bufB = x1
    rowstats_k<<<M_TOT / 4, blk, 0, stream>>>(bufC, bufD, rs);
    gemm_k<A_LN, 2, E_RES, 0, 0, 0><<<GG, blk, 0, stream>>>(
        bufC, bufD, fc5_w, fc5_b, x, rs, ln_w, ln_b, nullptr, bufB);
    // fused qkv
    qkv_k<<<GG, blk, 0, stream>>>(x, q_w, q_b, k_w, k_b, v_w, v_b, bufA, bufC, bufD);
    // window attention -> bufA
    attn_k<<<B_SZ * 64, blk, 0, stream>>>(bufA, bufC, bufD, bufA);
    // BN stats -> params
    bnstats1_k<<<512, blk, 0, stream>>>(bufA, accum);
    bnstats2_k<<<512, blk, 0, stream>>>(bufA, bn1_g, bn1_b, accum);
    bnparams_k<<<1, 128, 0, stream>>>(accum, bn1_g, bn1_b, bn2_g, bn2_b, bnp);
    // fc6 on [x1 | bn2(relu(bn1(att)))] -> d_out (f32)
    gemm_k<A_BN, 2, E_BIAS, 0, 0, 1><<<GG, blk, 0, stream>>>(
        bufB, bufA, fc6_w, fc6_b, nullptr, nullptr, nullptr, nullptr, bnp, d_out);
}

// Round 4
// 633.310 us; speedup vs baseline: 1.4183x; 1.1371x over previous
//
#include <hip/hip_runtime.h>
#include <hip/hip_bf16.h>
#include <cstdint>
#include <cstddef>

typedef __bf16 bf16_t;
typedef __bf16 bf16x8 __attribute__((ext_vector_type(8)));
typedef float f32x4 __attribute__((ext_vector_type(4)));

#define B_SZ 32
#define H_SZ 56
#define W_SZ 56
#define N_TOK 3136
#define CH 128
#define M_TOT 100352

enum { A_FLAT = 0, A_WROLL, A_LN, A_BN };
enum { E_BIAS = 0, E_GELU, E_RES };

__device__ __forceinline__ float bf2f(bf16_t v) { return (float)v; }
__device__ __forceinline__ unsigned short bfbits(float v) {
    bf16_t b = (bf16_t)v; unsigned short u; __builtin_memcpy(&u, &b, 2); return u;
}

// ---------------------------------------------------------------------------
// Transpose: x[B,N,C] f32 -> xT[B,C,N] bf16. 64 tokens per block.
// ---------------------------------------------------------------------------
__global__ __launch_bounds__(256)
void transpose_k(const float* __restrict__ x, bf16_t* __restrict__ xT)
{
    __shared__ bf16_t T[128][70];
    const int tid = threadIdx.x;
    const int mbase = blockIdx.x * 64;
    const int bimg = mbase / N_TOK;
    const int n0 = mbase - bimg * N_TOK;
    for (int idx = tid; idx < 64 * 32; idx += 256) {
        const int tok = idx >> 5, cg = idx & 31;
        float4 u = *(const float4*)(x + (size_t)(mbase + tok) * CH + cg * 4);
        T[cg * 4 + 0][tok] = (bf16_t)u.x;
        T[cg * 4 + 1][tok] = (bf16_t)u.y;
        T[cg * 4 + 2][tok] = (bf16_t)u.z;
        T[cg * 4 + 3][tok] = (bf16_t)u.w;
    }
    __syncthreads();
    const uint* T32 = (const uint*)&T[0][0]; // [128][35]
    for (int idx = tid; idx < 128 * 8; idx += 256) {
        const int c = idx >> 3, chunk = idx & 7;
        uint4 o;
        o.x = T32[c * 35 + chunk * 4 + 0];
        o.y = T32[c * 35 + chunk * 4 + 1];
        o.z = T32[c * 35 + chunk * 4 + 2];
        o.w = T32[c * 35 + chunk * 4 + 3];
        *(uint4*)(xT + ((size_t)(bimg * 128 + c)) * N_TOK + n0 + chunk * 8) = o;
    }
}

// ---------------------------------------------------------------------------
// MFMA GEMM: out[M,128] = f(A) @ W[K,128] + bias (+epilogue). 64x128 tile.
// ---------------------------------------------------------------------------
template<int AMODE, int KHALVES, int EPI, int WDIR, int OTRANS, int OF32>
__global__ __launch_bounds__(256)
void gemm_k(const bf16_t* __restrict__ A0, const bf16_t* __restrict__ A1,
            const float* __restrict__ Wt, const float* __restrict__ bias,
            const float* __restrict__ resid,
            const float* __restrict__ rowst,
            const float* __restrict__ lnw, const float* __restrict__ lnb,
            const float* __restrict__ bnp,
            void* __restrict__ outv)
{
    __shared__ __align__(16) bf16_t As[64][136];
    __shared__ __align__(16) bf16_t Bs[128][136];
    const int tid = threadIdx.x;
    const int mbase = blockIdx.x * 64;
    const int bimg = mbase / N_TOK;
    const int n0 = mbase - bimg * N_TOK;
    const int lane = tid & 63;
    const int wv = tid >> 6;
    const int qd = lane >> 4;
    const int mr = lane & 15;

    f32x4 acc[4][2];
#pragma unroll
    for (int i = 0; i < 4; ++i)
#pragma unroll
        for (int j = 0; j < 2; ++j) { f32x4 z = {0.f,0.f,0.f,0.f}; acc[i][j] = z; }

    for (int kh = 0; kh < KHALVES; ++kh) {
        if (kh) __syncthreads();
        // ---- stage A tile ----
        if (AMODE == A_FLAT || AMODE == A_WROLL) {
            for (int idx = tid; idx < 128 * 8; idx += 256) {
                const int c = idx >> 3, chunk = idx & 7;
                const int cm = (c >= 112) ? c - 112 : (c >= 56 ? c - 56 : c);
                const bf16_t* crow = A0 + ((size_t)(bimg * 128 + c)) * N_TOK;
                if (AMODE == A_FLAT) {
                    int t = n0 + chunk * 8 + N_TOK - 56 * cm;
                    if (t >= N_TOK) t -= N_TOK;
                    uint4 u = *(const uint4*)(crow + t);
                    const bf16_t* up = (const bf16_t*)&u;
#pragma unroll
                    for (int j = 0; j < 8; ++j) As[chunk * 8 + j][c] = up[j];
                } else {
                    const int nl = n0 + chunk * 8;
                    const int h = nl / 56;
                    const int w0 = nl - h * 56;
                    int ws = (WDIR > 0) ? (w0 + cm) : (w0 + 56 - cm);
                    if (ws >= 56) ws -= 56;
                    const bf16_t* hrow = crow + h * 56;
                    if (ws <= 48) {
                        uint4 u = *(const uint4*)(hrow + ws);
                        const bf16_t* up = (const bf16_t*)&u;
#pragma unroll
                        for (int j = 0; j < 8; ++j) As[chunk * 8 + j][c] = up[j];
                    } else {
#pragma unroll
                        for (int j = 0; j < 8; ++j) {
                            int wj = ws + j; if (wj >= 56) wj -= 56;
                            As[chunk * 8 + j][c] = hrow[wj];
                        }
                    }
                }
            }
        } else if (AMODE == A_LN) {
            for (int idx = tid; idx < 64 * 16; idx += 256) {
                const int row = idx >> 4, ck = idx & 15;
                const int rowg = mbase + row;
                const bf16_t* src = kh ? A1 : A0;
                uint4 u = *(const uint4*)(src + (size_t)rowg * CH + ck * 8);
                const bf16_t* up = (const bf16_t*)&u;
                const float mean = rowst[2 * rowg];
                const float rstd = rowst[2 * rowg + 1];
                const int cabs = kh * 128 + ck * 8;
                bf16_t t[8];
#pragma unroll
                for (int j = 0; j < 8; ++j) {
                    float v = (bf2f(up[j]) - mean) * rstd;
                    v = v * lnw[cabs + j] + lnb[cabs + j];
                    t[j] = (bf16_t)v;
                }
                *(uint4*)(&As[row][ck * 8]) = *(const uint4*)t;
            }
        } else { // A_BN
            for (int idx = tid; idx < 64 * 16; idx += 256) {
                const int row = idx >> 4, ck = idx & 15;
                const int rowg = mbase + row;
                if (kh == 0) {
                    uint4 u = *(const uint4*)(A0 + (size_t)rowg * CH + ck * 8);
                    *(uint4*)(&As[row][ck * 8]) = u;
                } else {
                    uint4 u = *(const uint4*)(A1 + (size_t)rowg * CH + ck * 8);
                    const bf16_t* up = (const bf16_t*)&u;
                    bf16_t t[8];
#pragma unroll
                    for (int j = 0; j < 8; ++j) {
                        const int c = ck * 8 + j;
                        float z = fmaxf(0.f, bf2f(up[j]) * bnp[c] + bnp[128 + c]);
                        t[j] = (bf16_t)(z * bnp[256 + c] + bnp[384 + c]);
                    }
                    *(uint4*)(&As[row][ck * 8]) = *(const uint4*)t;
                }
            }
        }
        // ---- stage B: Bs[n][k] from f32 W[K][128] ----
        for (int idx = tid; idx < 128 * 16; idx += 256) {
            const int kk = idx >> 4, cn = idx & 15;
            const float* wp = Wt + (size_t)(kh * 128 + kk) * CH + cn * 8;
            float4 u0 = *(const float4*)wp;
            float4 u1 = *(const float4*)(wp + 4);
            Bs[cn * 8 + 0][kk] = (bf16_t)u0.x;
            Bs[cn * 8 + 1][kk] = (bf16_t)u0.y;
            Bs[cn * 8 + 2][kk] = (bf16_t)u0.z;
            Bs[cn * 8 + 3][kk] = (bf16_t)u0.w;
            Bs[cn * 8 + 4][kk] = (bf16_t)u1.x;
            Bs[cn * 8 + 5][kk] = (bf16_t)u1.y;
            Bs[cn * 8 + 6][kk] = (bf16_t)u1.z;
            Bs[cn * 8 + 7][kk] = (bf16_t)u1.w;
        }
        __syncthreads();
#pragma unroll
        for (int kt = 0; kt < 4; ++kt) {
            bf16x8 af[4], bfr[2];
#pragma unroll
            for (int mt = 0; mt < 4; ++mt)
                af[mt] = *(const bf16x8*)(&As[mt * 16 + mr][kt * 32 + qd * 8]);
#pragma unroll
            for (int nt = 0; nt < 2; ++nt)
                bfr[nt] = *(const bf16x8*)(&Bs[wv * 32 + nt * 16 + mr][kt * 32 + qd * 8]);
#pragma unroll
            for (int mt = 0; mt < 4; ++mt)
#pragma unroll
                for (int nt = 0; nt < 2; ++nt)
                    acc[mt][nt] = __builtin_amdgcn_mfma_f32_16x16x32_bf16(
                        af[mt], bfr[nt], acc[mt][nt], 0, 0, 0);
        }
    }
    // ---- epilogue ----
    if (OTRANS) {
        __syncthreads();
        uint* T32 = (uint*)&Bs[0][0];  // bf16 [128][70] as uint [128][35]
#pragma unroll
        for (int mt = 0; mt < 4; ++mt)
#pragma unroll
            for (int nt = 0; nt < 2; ++nt) {
                const int col = wv * 32 + nt * 16 + mr;
                const float bb = bias[col];
#pragma unroll
                for (int rp = 0; rp < 2; ++rp) {
                    float v0 = acc[mt][nt][2 * rp] + bb;
                    float v1 = acc[mt][nt][2 * rp + 1] + bb;
                    if (EPI == E_GELU) {
                        v0 = 0.5f * v0 * (1.f + erff(v0 * 0.70710678118654752f));
                        v1 = 0.5f * v1 * (1.f + erff(v1 * 0.70710678118654752f));
                    }
                    T32[col * 35 + mt * 8 + qd * 2 + rp] =
                        (uint)bfbits(v0) | ((uint)bfbits(v1) << 16);
                }
            }
        __syncthreads();
        const int c = tid >> 1, half = tid & 1;
        uint r[16];
#pragma unroll
        for (int j = 0; j < 16; ++j) r[j] = T32[c * 35 + half * 16 + j];
        bf16_t* op = (bf16_t*)outv + ((size_t)(bimg * 128 + c)) * N_TOK + n0 + half * 32;
        uint4 o0 = {r[0], r[1], r[2], r[3]};
        uint4 o1 = {r[4], r[5], r[6], r[7]};
        uint4 o2 = {r[8], r[9], r[10], r[11]};
        uint4 o3 = {r[12], r[13], r[14], r[15]};
        ((uint4*)op)[0] = o0; ((uint4*)op)[1] = o1;
        ((uint4*)op)[2] = o2; ((uint4*)op)[3] = o3;
    } else {
#pragma unroll
        for (int mt = 0; mt < 4; ++mt)
#pragma unroll
            for (int nt = 0; nt < 2; ++nt) {
                const int col = wv * 32 + nt * 16 + mr;
                const float bb = bias[col];
#pragma unroll
                for (int r = 0; r < 4; ++r) {
                    const int rowg = mbase + mt * 16 + qd * 4 + r;
                    float v = acc[mt][nt][r] + bb;
                    if (EPI == E_GELU) v = 0.5f * v * (1.f + erff(v * 0.70710678118654752f));
                    if (EPI == E_RES)  v += resid[(size_t)rowg * CH + col];
                    if (OF32) ((float*)outv)[(size_t)rowg * CH + col] = v;
                    else ((bf16_t*)outv)[(size_t)rowg * CH + col] = (bf16_t)v;
                }
            }
    }
}

// ---------------------------------------------------------------------------
// Fused q/k/v: stage x-tile (f32->bf16) once, loop 3 conv weights [128][128].
// ---------------------------------------------------------------------------
__global__ __launch_bounds__(256)
void qkv_k(const float* __restrict__ x,
           const float* __restrict__ qw, const float* __restrict__ qb,
           const float* __restrict__ kw, const float* __restrict__ kb,
           const float* __restrict__ vw, const float* __restrict__ vb,
           bf16_t* __restrict__ qo, bf16_t* __restrict__ ko, bf16_t* __restrict__ vo)
{
    __shared__ __align__(16) bf16_t As[64][136];
    __shared__ __align__(16) bf16_t Bs[128][136];
    const int tid = threadIdx.x;
    const int mbase = blockIdx.x * 64;
    const int lane = tid & 63;
    const int wv = tid >> 6;
    const int qd = lane >> 4;
    const int mr = lane & 15;

    for (int idx = tid; idx < 64 * 16; idx += 256) {
        const int row = idx >> 4, ck = idx & 15;
        const float* p = x + (size_t)(mbase + row) * CH + ck * 8;
        float4 u0 = *(const float4*)p;
        float4 u1 = *(const float4*)(p + 4);
        bf16_t t[8] = {(bf16_t)u0.x, (bf16_t)u0.y, (bf16_t)u0.z, (bf16_t)u0.w,
                       (bf16_t)u1.x, (bf16_t)u1.y, (bf16_t)u1.z, (bf16_t)u1.w};
        *(uint4*)(&As[row][ck * 8]) = *(const uint4*)t;
    }
    const float* ws3[3] = {qw, kw, vw};
    const float* bs3[3] = {qb, kb, vb};
    bf16_t* os3[3] = {qo, ko, vo};
    for (int s = 0; s < 3; ++s) {
        __syncthreads();
        for (int idx = tid; idx < 128 * 16; idx += 256) {
            const int nn = idx >> 4, ck = idx & 15;
            const float* wp = ws3[s] + (size_t)nn * CH + ck * 8;
            float4 u0 = *(const float4*)wp;
            float4 u1 = *(const float4*)(wp + 4);
            bf16_t t[8] = {(bf16_t)u0.x, (bf16_t)u0.y, (bf16_t)u0.z, (bf16_t)u0.w,
                           (bf16_t)u1.x, (bf16_t)u1.y, (bf16_t)u1.z, (bf16_t)u1.w};
            *(uint4*)(&Bs[nn][ck * 8]) = *(const uint4*)t;
        }
        __syncthreads();
        f32x4 acc[4][2];
#pragma unroll
        for (int i = 0; i < 4; ++i)
#pragma unroll
            for (int j = 0; j < 2; ++j) { f32x4 z = {0.f,0.f,0.f,0.f}; acc[i][j] = z; }
#pragma unroll
        for (int kt = 0; kt < 4; ++kt) {
            bf16x8 af[4], bfr[2];
#pragma unroll
            for (int mt = 0; mt < 4; ++mt)
                af[mt] = *(const bf16x8*)(&As[mt * 16 + mr][kt * 32 + qd * 8]);
#pragma unroll
            for (int nt = 0; nt < 2; ++nt)
                bfr[nt] = *(const bf16x8*)(&Bs[wv * 32 + nt * 16 + mr][kt * 32 + qd * 8]);
#pragma unroll
            for (int mt = 0; mt < 4; ++mt)
#pragma unroll
                for (int nt = 0; nt < 2; ++nt)
                    acc[mt][nt] = __builtin_amdgcn_mfma_f32_16x16x32_bf16(
                        af[mt], bfr[nt], acc[mt][nt], 0, 0, 0);
        }
        bf16_t* out = os3[s];
#pragma unroll
        for (int mt = 0; mt < 4; ++mt)
#pragma unroll
            for (int nt = 0; nt < 2; ++nt) {
                const int col = wv * 32 + nt * 16 + mr;
                const float bb = bs3[s][col];
#pragma unroll
                for (int r = 0; r < 4; ++r) {
                    const int rowg = mbase + mt * 16 + qd * 4 + r;
                    out[(size_t)rowg * CH + col] = (bf16_t)(acc[mt][nt][r] + bb);
                }
            }
    }
}

// ---------------------------------------------------------------------------
__global__ __launch_bounds__(256)
void rowstats_k(const bf16_t* __restrict__ x1p, const bf16_t* __restrict__ x2p,
                float* __restrict__ rs)
{
    const int row = blockIdx.x * 4 + (threadIdx.x >> 6);
    const int lane = threadIdx.x & 63;
    const bf16_t* p1 = x1p + (size_t)row * CH + lane * 2;
    const bf16_t* p2 = x2p + (size_t)row * CH + lane * 2;
    float a0 = bf2f(p1[0]), a1 = bf2f(p1[1]);
    float b0 = bf2f(p2[0]), b1 = bf2f(p2[1]);
    float s = a0 + a1 + b0 + b1;
    float sq = a0 * a0 + a1 * a1 + b0 * b0 + b1 * b1;
#pragma unroll
    for (int off = 32; off > 0; off >>= 1) {
        s += __shfl_down(s, off);
        sq += __shfl_down(sq, off);
    }
    if (lane == 0) {
        float mean = s * (1.f / 256.f);
        float var = sq * (1.f / 256.f) - mean * mean;
        rs[2 * row] = mean;
        rs[2 * row + 1] = rsqrtf(var + 1e-5f);
    }
}

// ---------------------------------------------------------------------------
// MFMA window attention, one block per 7x7 window (2048 blocks), padded to 64
// tokens. Fuses BN pass-1 stats (per-channel sum/sumsq of the output).
// og may alias qg (per-window partition; Q staged to LDS before writes).
// ---------------------------------------------------------------------------
__global__ __launch_bounds__(256)
void attn_k(const bf16_t* __restrict__ qg, const bf16_t* __restrict__ kg,
            const bf16_t* __restrict__ vg, bf16_t* __restrict__ og,
            float* __restrict__ accum)
{
    __shared__ __align__(16) bf16_t R0[64 * 136]; // Qs, then f32 scores [64][68]
    __shared__ __align__(16) bf16_t R1[64 * 136]; // Ks, then P bf16 [64][72]
    __shared__ __align__(16) bf16_t R2[128 * 72]; // V^T [c][j], stride 72
    __shared__ float bnacc[256];
    const int tid = threadIdx.x;
    const int blk = blockIdx.x;
    const int b = blk >> 6;
    const int wy = (blk >> 3) & 7;
    const int wx = blk & 7;
    const int lane = tid & 63;
    const int wv = tid >> 6;
    const int qd = lane >> 4;
    const int mr = lane & 15;

    bnacc[tid] = 0.f;
    // ---- stage Q,K [64 tok][128 c], rows >=49 zeroed ----
    for (int idx = tid; idx < 64 * 16; idx += 256) {
        const int i = idx >> 4, ck = idx & 15;
        uint4 uq = {0, 0, 0, 0}, uk = {0, 0, 0, 0};
        if (i < 49) {
            const int n = (wy * 7 + i / 7) * 56 + wx * 7 + (i % 7);
            const size_t off = ((size_t)b * N_TOK + n) * CH + ck * 8;
            uq = *(const uint4*)(qg + off);
            uk = *(const uint4*)(kg + off);
        }
        *(uint4*)(&R0[i * 136 + ck * 8]) = uq;
        *(uint4*)(&R1[i * 136 + ck * 8]) = uk;
    }
    // ---- stage V^T[c][j] (c-consecutive lanes: coalesced global reads) ----
    {
        const int c = tid & 127, half = tid >> 7;
#pragma unroll
        for (int jc = half * 4; jc < half * 4 + 4; ++jc) {
            bf16_t t[8];
#pragma unroll
            for (int jj = 0; jj < 8; ++jj) {
                const int j = jc * 8 + jj;
                bf16_t v = (bf16_t)0.f;
                if (j < 49) {
                    const int n = (wy * 7 + j / 7) * 56 + wx * 7 + (j % 7);
                    v = vg[((size_t)b * N_TOK + n) * CH + c];
                }
                t[jj] = v;
            }
            *(uint4*)(&R2[c * 72 + jc * 8]) = *(const uint4*)t;
        }
    }
    __syncthreads();
    // ---- QK^T: wave wv -> q rows [wv*16, wv*16+16), 4 key tiles ----
    bf16x8 aq[4];
#pragma unroll
    for (int kt = 0; kt < 4; ++kt)
        aq[kt] = *(const bf16x8*)(&R0[(wv * 16 + mr) * 136 + kt * 32 + qd * 8]);
    f32x4 sacc[4];
#pragma unroll
    for (int nt = 0; nt < 4; ++nt) {
        f32x4 a = {0.f, 0.f, 0.f, 0.f};
#pragma unroll
        for (int kt = 0; kt < 4; ++kt) {
            bf16x8 bk = *(const bf16x8*)(&R1[(nt * 16 + mr) * 136 + kt * 32 + qd * 8]);
            a = __builtin_amdgcn_mfma_f32_16x16x32_bf16(aq[kt], bk, a, 0, 0, 0);
        }
        sacc[nt] = a;
    }
    __syncthreads();
    // ---- scores -> f32 LDS (scale + key mask) ----
    float* Ss = (float*)R0; // [64][68]
#pragma unroll
    for (int nt = 0; nt < 4; ++nt) {
        const int j = nt * 16 + mr;
#pragma unroll
        for (int r = 0; r < 4; ++r) {
            const int q = wv * 16 + qd * 4 + r;
            Ss[q * 68 + j] = (j < 49) ? sacc[nt][r] * 0.088388347648318447f : -1e30f;
        }
    }
    __syncthreads();
    // ---- softmax per row -> P bf16 [64][72] in R1 ----
    bf16_t* Ps = R1;
    if (tid < 64) {
        float mx = -1e30f;
        for (int j = 0; j < 64; ++j) mx = fmaxf(mx, Ss[tid * 68 + j]);
        float sum = 0.f;
        for (int j = 0; j < 64; ++j) {
            float e = __expf(Ss[tid * 68 + j] - mx);
            Ss[tid * 68 + j] = e; sum += e;
        }
        const float inv = 1.f / sum;
        for (int j = 0; j < 64; ++j) Ps[tid * 72 + j] = (bf16_t)(Ss[tid * 68 + j] * inv);
    }
    __syncthreads();
    // ---- PV: wave wv -> q rows [wv*16,+16) x 8 channel tiles, K=64 ----
    bf16x8 ap[2];
    ap[0] = *(const bf16x8*)(&Ps[(wv * 16 + mr) * 72 + qd * 8]);
    ap[1] = *(const bf16x8*)(&Ps[(wv * 16 + mr) * 72 + 32 + qd * 8]);
    f32x4 oacc[8];
#pragma unroll
    for (int nt = 0; nt < 8; ++nt) {
        f32x4 a = {0.f, 0.f, 0.f, 0.f};
#pragma unroll
        for (int kt = 0; kt < 2; ++kt) {
            bf16x8 bv = *(const bf16x8*)(&R2[(nt * 16 + mr) * 72 + kt * 32 + qd * 8]);
            a = __builtin_amdgcn_mfma_f32_16x16x32_bf16(ap[kt], bv, a, 0, 0, 0);
        }
        oacc[nt] = a;
    }
    // ---- epilogue: write out + BN pass-1 partials ----
#pragma unroll
    for (int nt = 0; nt < 8; ++nt) {
        const int c = nt * 16 + mr;
        float s = 0.f, sq = 0.f;
#pragma unroll
        for (int r = 0; r < 4; ++r) {
            const int q = wv * 16 + qd * 4 + r;
            if (q < 49) {
                const float v = oacc[nt][r];
                const int n = (wy * 7 + q / 7) * 56 + wx * 7 + (q % 7);
                og[((size_t)b * N_TOK + n) * CH + c] = (bf16_t)v;
                s += v; sq += v * v;
            }
        }
        atomicAdd(&bnacc[c], s);
        atomicAdd(&bnacc[128 + c], sq);
    }
    __syncthreads();
    if (tid < 128) {
        atomicAdd(&accum[tid], bnacc[tid]);
        atomicAdd(&accum[128 + tid], bnacc[128 + tid]);
    }
}

// ---------------------------------------------------------------------------
__global__ __launch_bounds__(256)
void bnstats2_k(const bf16_t* __restrict__ att, const float* __restrict__ g1,
                const float* __restrict__ b1, float* __restrict__ accum)
{
    __shared__ float ls[256], lq[256];
    const int c = threadIdx.x & 127;
    const int half = threadIdx.x >> 7;
    const float m = accum[c] * (1.f / (float)M_TOT);
    const float var = accum[128 + c] * (1.f / (float)M_TOT) - m * m;
    const float rstd = rsqrtf(var + 1e-5f);
    const float scl = g1[c] * rstd;
    const float sh = b1[c] - m * scl;
    const size_t rowbase = (size_t)blockIdx.x * 196;
    float s = 0.f, sq = 0.f;
    for (int r = half; r < 196; r += 2) {
        float z = fmaxf(0.f, bf2f(att[(rowbase + r) * CH + c]) * scl + sh);
        s += z; sq += z * z;
    }
    ls[threadIdx.x] = s; lq[threadIdx.x] = sq;
    __syncthreads();
    if (threadIdx.x < 128) {
        atomicAdd(&accum[256 + c], ls[threadIdx.x] + ls[threadIdx.x + 128]);
        atomicAdd(&accum[384 + c], lq[threadIdx.x] + lq[threadIdx.x + 128]);
    }
}

__global__ void bnparams_k(const float* __restrict__ accum,
                           const float* __restrict__ g1, const float* __restrict__ b1,
                           const float* __restrict__ g2, const float* __restrict__ b2,
                           float* __restrict__ bnp)
{
    const int c = threadIdx.x;
    const float inv = 1.f / (float)M_TOT;
    float m1 = accum[c] * inv;
    float v1 = accum[128 + c] * inv - m1 * m1;
    float rs1 = rsqrtf(v1 + 1e-5f);
    float s1 = g1[c] * rs1;
    float sh1 = b1[c] - m1 * s1;
    float m2 = accum[256 + c] * inv;
    float v2 = accum[384 + c] * inv - m2 * m2;
    float rs2 = rsqrtf(v2 + 1e-5f);
    float s2 = g2[c] * rs2;
    float sh2 = b2[c] - m2 * s2;
    bnp[c] = s1; bnp[128 + c] = sh1; bnp[256 + c] = s2; bnp[384 + c] = sh2;
}

__global__ void zero_k(float* __restrict__ p) { p[threadIdx.x] = 0.f; }

// ---------------------------------------------------------------------------
extern "C" void kernel_launch(void* const* d_in, const int* in_sizes, int n_in,
                              void* d_out, int out_size, void* d_ws, size_t ws_size,
                              hipStream_t stream)
{
    (void)in_sizes; (void)n_in; (void)out_size; (void)ws_size;
    const float* x     = (const float*)d_in[0];
    const float* fc1_w = (const float*)d_in[1];
    const float* fc1_b = (const float*)d_in[2];
    const float* fc2_w = (const float*)d_in[3];
    const float* fc2_b = (const float*)d_in[4];
    const float* fc3_w = (const float*)d_in[5];
    const float* fc3_b = (const float*)d_in[6];
    const float* fc4_w = (const float*)d_in[7];
    const float* fc4_b = (const float*)d_in[8];
    const float* fc5_w = (const float*)d_in[9];
    const float* fc5_b = (const float*)d_in[10];
    const float* fc6_w = (const float*)d_in[11];
    const float* fc6_b = (const float*)d_in[12];
    const float* ln_w  = (const float*)d_in[13];
    const float* ln_b  = (const float*)d_in[14];
    const float* q_w   = (const float*)d_in[15];
    const float* q_b   = (const float*)d_in[16];
    const float* k_w   = (const float*)d_in[17];
    const float* k_b   = (const float*)d_in[18];
    const float* v_w   = (const float*)d_in[19];
    const float* v_b   = (const float*)d_in[20];
    const float* bn1_g = (const float*)d_in[21];
    const float* bn1_b = (const float*)d_in[22];
    const float* bn2_g = (const float*)d_in[23];
    const float* bn2_b = (const float*)d_in[24];

    char* ws = (char*)d_ws;
    const size_t SZB = (size_t)M_TOT * CH * sizeof(bf16_t); // 25.7 MB
    bf16_t* bufA = (bf16_t*)(ws);            // xT -> q -> attn out
    bf16_t* bufB = (bf16_t*)(ws + SZB);      // y1T -> y3T -> x1
    bf16_t* bufC = (bf16_t*)(ws + 2 * SZB);  // x_1+x -> k
    bf16_t* bufD = (bf16_t*)(ws + 3 * SZB);  // x_2+x -> v
    float*  rs   = (float*)(ws + 4 * SZB);
    float*  accum = (float*)(ws + 4 * SZB + (size_t)M_TOT * 2 * sizeof(float));
    float*  bnp  = accum + 512;

    const dim3 blk(256);
    const int GG = M_TOT / 64; // 1568

    zero_k<<<1, 512, 0, stream>>>(accum);
    transpose_k<<<GG, blk, 0, stream>>>(x, bufA);
    // branch 1: fc1 (H-roll +c) + GELU -> y1T [C,N]
    gemm_k<A_FLAT, 1, E_GELU, 0, 1, 0><<<GG, blk, 0, stream>>>(
        bufA, nullptr, fc1_w, fc1_b, nullptr, nullptr, nullptr, nullptr, nullptr, bufB);
    // fc2 (W-roll +c on y1T) + x -> bufC [N,C]
    gemm_k<A_WROLL, 1, E_RES, -1, 0, 0><<<GG, blk, 0, stream>>>(
        bufB, nullptr, fc2_w, fc2_b, x, nullptr, nullptr, nullptr, nullptr, bufC);
    // branch 2: fc3 (W-roll -c) + GELU -> y3T [C,N]
    gemm_k<A_WROLL, 1, E_GELU, 1, 1, 0><<<GG, blk, 0, stream>>>(
        bufA, nullptr, fc3_w, fc3_b, nullptr, nullptr, nullptr, nullptr, nullptr, bufB);
    // fc4 (H-roll +c on y3T) + x -> bufD [N,C]
    gemm_k<A_FLAT, 1, E_RES, 0, 0, 0><<<GG, blk, 0, stream>>>(
        bufB, nullptr, fc4_w, fc4_b, x, nullptr, nullptr, nullptr, nullptr, bufD);
    // LN stats + fc5 (+x) -> bufB = x1
    rowstats_k<<<M_TOT / 4, blk, 0, stream>>>(bufC, bufD, rs);
    gemm_k<A_LN, 2, E_RES, 0, 0, 0><<<GG, blk, 0, stream>>>(
        bufC, bufD, fc5_w, fc5_b, x, rs, ln_w, ln_b, nullptr, bufB);
    // fused qkv
    qkv_k<<<GG, blk, 0, stream>>>(x, q_w, q_b, k_w, k_b, v_w, v_b, bufA, bufC, bufD);
    // MFMA window attention (+ fused BN pass-1 stats) -> bufA
    attn_k<<<B_SZ * 64, blk, 0, stream>>>(bufA, bufC, bufD, bufA, accum);
    // BN pass-2 stats -> params
    bnstats2_k<<<512, blk, 0, stream>>>(bufA, bn1_g, bn1_b, accum);
    bnparams_k<<<1, 128, 0, stream>>>(accum, bn1_g, bn1_b, bn2_g, bn2_b, bnp);
    // fc6 on [x1 | bn2(relu(bn1(att)))] -> d_out (f32)
    gemm_k<A_BN, 2, E_BIAS, 0, 0, 1><<<GG, blk, 0, stream>>>(
        bufB, bufA, fc6_w, fc6_b, nullptr, nullptr, nullptr, nullptr, bnp, d_out);
}

// Round 5
// 625.039 us; speedup vs baseline: 1.4371x; 1.0132x over previous
//
#include <hip/hip_runtime.h>
#include <hip/hip_bf16.h>
#include <cstdint>
#include <cstddef>

typedef __bf16 bf16_t;
typedef __bf16 bf16x8 __attribute__((ext_vector_type(8)));
typedef float f32x4 __attribute__((ext_vector_type(4)));

#define B_SZ 32
#define H_SZ 56
#define W_SZ 56
#define N_TOK 3136
#define CH 128
#define M_TOT 100352

enum { A_FLAT = 0, A_WROLL, A_LN, A_BN };
enum { E_BIAS = 0, E_GELU, E_RES };

__device__ __forceinline__ float bf2f(bf16_t v) { return (float)v; }
__device__ __forceinline__ unsigned short bfbits(float v) {
    bf16_t b = (bf16_t)v; unsigned short u; __builtin_memcpy(&u, &b, 2); return u;
}

// ---------------------------------------------------------------------------
// Transpose: x[B,N,C] f32 -> xT[B,C,N] bf16. 64 tokens per block.
// ---------------------------------------------------------------------------
__global__ __launch_bounds__(256)
void transpose_k(const float* __restrict__ x, bf16_t* __restrict__ xT)
{
    __shared__ bf16_t T[128][70];
    const int tid = threadIdx.x;
    const int mbase = blockIdx.x * 64;
    const int bimg = mbase / N_TOK;
    const int n0 = mbase - bimg * N_TOK;
    for (int idx = tid; idx < 64 * 32; idx += 256) {
        const int tok = idx >> 5, cg = idx & 31;
        float4 u = *(const float4*)(x + (size_t)(mbase + tok) * CH + cg * 4);
        T[cg * 4 + 0][tok] = (bf16_t)u.x;
        T[cg * 4 + 1][tok] = (bf16_t)u.y;
        T[cg * 4 + 2][tok] = (bf16_t)u.z;
        T[cg * 4 + 3][tok] = (bf16_t)u.w;
    }
    __syncthreads();
    const uint* T32 = (const uint*)&T[0][0]; // [128][35]
    for (int idx = tid; idx < 128 * 8; idx += 256) {
        const int c = idx >> 3, chunk = idx & 7;
        uint4 o;
        o.x = T32[c * 35 + chunk * 4 + 0];
        o.y = T32[c * 35 + chunk * 4 + 1];
        o.z = T32[c * 35 + chunk * 4 + 2];
        o.w = T32[c * 35 + chunk * 4 + 3];
        *(uint4*)(xT + ((size_t)(bimg * 128 + c)) * N_TOK + n0 + chunk * 8) = o;
    }
}

// ---------------------------------------------------------------------------
// MFMA GEMM: out[M,128] = f(A) @ W[K,128] + bias (+epilogue). 64x128 tile.
// ---------------------------------------------------------------------------
template<int AMODE, int KHALVES, int EPI, int WDIR, int OTRANS, int OF32>
__global__ __launch_bounds__(256)
void gemm_k(const bf16_t* __restrict__ A0, const bf16_t* __restrict__ A1,
            const float* __restrict__ Wt, const float* __restrict__ bias,
            const float* __restrict__ resid,
            const float* __restrict__ rowst,
            const float* __restrict__ lnw, const float* __restrict__ lnb,
            const float* __restrict__ bnp,
            void* __restrict__ outv)
{
    __shared__ __align__(16) bf16_t As[64][136];
    __shared__ __align__(16) bf16_t Bs[128][136];
    const int tid = threadIdx.x;
    const int mbase = blockIdx.x * 64;
    const int bimg = mbase / N_TOK;
    const int n0 = mbase - bimg * N_TOK;
    const int lane = tid & 63;
    const int wv = tid >> 6;
    const int qd = lane >> 4;
    const int mr = lane & 15;

    f32x4 acc[4][2];
#pragma unroll
    for (int i = 0; i < 4; ++i)
#pragma unroll
        for (int j = 0; j < 2; ++j) { f32x4 z = {0.f,0.f,0.f,0.f}; acc[i][j] = z; }

    for (int kh = 0; kh < KHALVES; ++kh) {
        if (kh) __syncthreads();
        // ---- stage A tile ----
        if (AMODE == A_FLAT || AMODE == A_WROLL) {
            for (int idx = tid; idx < 128 * 8; idx += 256) {
                const int c = idx >> 3, chunk = idx & 7;
                const int cm = (c >= 112) ? c - 112 : (c >= 56 ? c - 56 : c);
                const bf16_t* crow = A0 + ((size_t)(bimg * 128 + c)) * N_TOK;
                if (AMODE == A_FLAT) {
                    int t = n0 + chunk * 8 + N_TOK - 56 * cm;
                    if (t >= N_TOK) t -= N_TOK;
                    uint4 u = *(const uint4*)(crow + t);
                    const bf16_t* up = (const bf16_t*)&u;
#pragma unroll
                    for (int j = 0; j < 8; ++j) As[chunk * 8 + j][c] = up[j];
                } else {
                    const int nl = n0 + chunk * 8;
                    const int h = nl / 56;
                    const int w0 = nl - h * 56;
                    int ws = (WDIR > 0) ? (w0 + cm) : (w0 + 56 - cm);
                    if (ws >= 56) ws -= 56;
                    const bf16_t* hrow = crow + h * 56;
                    if (ws <= 48) {
                        uint4 u = *(const uint4*)(hrow + ws);
                        const bf16_t* up = (const bf16_t*)&u;
#pragma unroll
                        for (int j = 0; j < 8; ++j) As[chunk * 8 + j][c] = up[j];
                    } else {
#pragma unroll
                        for (int j = 0; j < 8; ++j) {
                            int wj = ws + j; if (wj >= 56) wj -= 56;
                            As[chunk * 8 + j][c] = hrow[wj];
                        }
                    }
                }
            }
        } else if (AMODE == A_LN) {
            for (int idx = tid; idx < 64 * 16; idx += 256) {
                const int row = idx >> 4, ck = idx & 15;
                const int rowg = mbase + row;
                const bf16_t* src = kh ? A1 : A0;
                uint4 u = *(const uint4*)(src + (size_t)rowg * CH + ck * 8);
                const bf16_t* up = (const bf16_t*)&u;
                const float mean = rowst[2 * rowg];
                const float rstd = rowst[2 * rowg + 1];
                const int cabs = kh * 128 + ck * 8;
                bf16_t t[8];
#pragma unroll
                for (int j = 0; j < 8; ++j) {
                    float v = (bf2f(up[j]) - mean) * rstd;
                    v = v * lnw[cabs + j] + lnb[cabs + j];
                    t[j] = (bf16_t)v;
                }
                *(uint4*)(&As[row][ck * 8]) = *(const uint4*)t;
            }
        } else { // A_BN
            for (int idx = tid; idx < 64 * 16; idx += 256) {
                const int row = idx >> 4, ck = idx & 15;
                const int rowg = mbase + row;
                if (kh == 0) {
                    uint4 u = *(const uint4*)(A0 + (size_t)rowg * CH + ck * 8);
                    *(uint4*)(&As[row][ck * 8]) = u;
                } else {
                    uint4 u = *(const uint4*)(A1 + (size_t)rowg * CH + ck * 8);
                    const bf16_t* up = (const bf16_t*)&u;
                    bf16_t t[8];
#pragma unroll
                    for (int j = 0; j < 8; ++j) {
                        const int c = ck * 8 + j;
                        float z = fmaxf(0.f, bf2f(up[j]) * bnp[c] + bnp[128 + c]);
                        t[j] = (bf16_t)(z * bnp[256 + c] + bnp[384 + c]);
                    }
                    *(uint4*)(&As[row][ck * 8]) = *(const uint4*)t;
                }
            }
        }
        // ---- stage B: Bs[n][k] from f32 W[K][128] ----
        for (int idx = tid; idx < 128 * 16; idx += 256) {
            const int kk = idx >> 4, cn = idx & 15;
            const float* wp = Wt + (size_t)(kh * 128 + kk) * CH + cn * 8;
            float4 u0 = *(const float4*)wp;
            float4 u1 = *(const float4*)(wp + 4);
            Bs[cn * 8 + 0][kk] = (bf16_t)u0.x;
            Bs[cn * 8 + 1][kk] = (bf16_t)u0.y;
            Bs[cn * 8 + 2][kk] = (bf16_t)u0.z;
            Bs[cn * 8 + 3][kk] = (bf16_t)u0.w;
            Bs[cn * 8 + 4][kk] = (bf16_t)u1.x;
            Bs[cn * 8 + 5][kk] = (bf16_t)u1.y;
            Bs[cn * 8 + 6][kk] = (bf16_t)u1.z;
            Bs[cn * 8 + 7][kk] = (bf16_t)u1.w;
        }
        __syncthreads();
#pragma unroll
        for (int kt = 0; kt < 4; ++kt) {
            bf16x8 af[4], bfr[2];
#pragma unroll
            for (int mt = 0; mt < 4; ++mt)
                af[mt] = *(const bf16x8*)(&As[mt * 16 + mr][kt * 32 + qd * 8]);
#pragma unroll
            for (int nt = 0; nt < 2; ++nt)
                bfr[nt] = *(const bf16x8*)(&Bs[wv * 32 + nt * 16 + mr][kt * 32 + qd * 8]);
#pragma unroll
            for (int mt = 0; mt < 4; ++mt)
#pragma unroll
                for (int nt = 0; nt < 2; ++nt)
                    acc[mt][nt] = __builtin_amdgcn_mfma_f32_16x16x32_bf16(
                        af[mt], bfr[nt], acc[mt][nt], 0, 0, 0);
        }
    }
    // ---- epilogue ----
    if (OTRANS) {
        __syncthreads();
        uint* T32 = (uint*)&Bs[0][0];  // bf16 [128][70] as uint [128][35]
#pragma unroll
        for (int mt = 0; mt < 4; ++mt)
#pragma unroll
            for (int nt = 0; nt < 2; ++nt) {
                const int col = wv * 32 + nt * 16 + mr;
                const float bb = bias[col];
#pragma unroll
                for (int rp = 0; rp < 2; ++rp) {
                    float v0 = acc[mt][nt][2 * rp] + bb;
                    float v1 = acc[mt][nt][2 * rp + 1] + bb;
                    if (EPI == E_GELU) {
                        v0 = 0.5f * v0 * (1.f + erff(v0 * 0.70710678118654752f));
                        v1 = 0.5f * v1 * (1.f + erff(v1 * 0.70710678118654752f));
                    }
                    T32[col * 35 + mt * 8 + qd * 2 + rp] =
                        (uint)bfbits(v0) | ((uint)bfbits(v1) << 16);
                }
            }
        __syncthreads();
        const int c = tid >> 1, half = tid & 1;
        uint r[16];
#pragma unroll
        for (int j = 0; j < 16; ++j) r[j] = T32[c * 35 + half * 16 + j];
        bf16_t* op = (bf16_t*)outv + ((size_t)(bimg * 128 + c)) * N_TOK + n0 + half * 32;
        uint4 o0 = {r[0], r[1], r[2], r[3]};
        uint4 o1 = {r[4], r[5], r[6], r[7]};
        uint4 o2 = {r[8], r[9], r[10], r[11]};
        uint4 o3 = {r[12], r[13], r[14], r[15]};
        ((uint4*)op)[0] = o0; ((uint4*)op)[1] = o1;
        ((uint4*)op)[2] = o2; ((uint4*)op)[3] = o3;
    } else {
#pragma unroll
        for (int mt = 0; mt < 4; ++mt)
#pragma unroll
            for (int nt = 0; nt < 2; ++nt) {
                const int col = wv * 32 + nt * 16 + mr;
                const float bb = bias[col];
#pragma unroll
                for (int r = 0; r < 4; ++r) {
                    const int rowg = mbase + mt * 16 + qd * 4 + r;
                    float v = acc[mt][nt][r] + bb;
                    if (EPI == E_GELU) v = 0.5f * v * (1.f + erff(v * 0.70710678118654752f));
                    if (EPI == E_RES)  v += resid[(size_t)rowg * CH + col];
                    if (OF32) ((float*)outv)[(size_t)rowg * CH + col] = v;
                    else ((bf16_t*)outv)[(size_t)rowg * CH + col] = (bf16_t)v;
                }
            }
    }
}

// ---------------------------------------------------------------------------
// Fused q/k/v: stage x-tile (f32->bf16) once, loop 3 conv weights [128][128].
// ---------------------------------------------------------------------------
__global__ __launch_bounds__(256)
void qkv_k(const float* __restrict__ x,
           const float* __restrict__ qw, const float* __restrict__ qb,
           const float* __restrict__ kw, const float* __restrict__ kb,
           const float* __restrict__ vw, const float* __restrict__ vb,
           bf16_t* __restrict__ qo, bf16_t* __restrict__ ko, bf16_t* __restrict__ vo)
{
    __shared__ __align__(16) bf16_t As[64][136];
    __shared__ __align__(16) bf16_t Bs[128][136];
    const int tid = threadIdx.x;
    const int mbase = blockIdx.x * 64;
    const int lane = tid & 63;
    const int wv = tid >> 6;
    const int qd = lane >> 4;
    const int mr = lane & 15;

    for (int idx = tid; idx < 64 * 16; idx += 256) {
        const int row = idx >> 4, ck = idx & 15;
        const float* p = x + (size_t)(mbase + row) * CH + ck * 8;
        float4 u0 = *(const float4*)p;
        float4 u1 = *(const float4*)(p + 4);
        bf16_t t[8] = {(bf16_t)u0.x, (bf16_t)u0.y, (bf16_t)u0.z, (bf16_t)u0.w,
                       (bf16_t)u1.x, (bf16_t)u1.y, (bf16_t)u1.z, (bf16_t)u1.w};
        *(uint4*)(&As[row][ck * 8]) = *(const uint4*)t;
    }
    const float* ws3[3] = {qw, kw, vw};
    const float* bs3[3] = {qb, kb, vb};
    bf16_t* os3[3] = {qo, ko, vo};
    for (int s = 0; s < 3; ++s) {
        __syncthreads();
        for (int idx = tid; idx < 128 * 16; idx += 256) {
            const int nn = idx >> 4, ck = idx & 15;
            const float* wp = ws3[s] + (size_t)nn * CH + ck * 8;
            float4 u0 = *(const float4*)wp;
            float4 u1 = *(const float4*)(wp + 4);
            bf16_t t[8] = {(bf16_t)u0.x, (bf16_t)u0.y, (bf16_t)u0.z, (bf16_t)u0.w,
                           (bf16_t)u1.x, (bf16_t)u1.y, (bf16_t)u1.z, (bf16_t)u1.w};
            *(uint4*)(&Bs[nn][ck * 8]) = *(const uint4*)t;
        }
        __syncthreads();
        f32x4 acc[4][2];
#pragma unroll
        for (int i = 0; i < 4; ++i)
#pragma unroll
            for (int j = 0; j < 2; ++j) { f32x4 z = {0.f,0.f,0.f,0.f}; acc[i][j] = z; }
#pragma unroll
        for (int kt = 0; kt < 4; ++kt) {
            bf16x8 af[4], bfr[2];
#pragma unroll
            for (int mt = 0; mt < 4; ++mt)
                af[mt] = *(const bf16x8*)(&As[mt * 16 + mr][kt * 32 + qd * 8]);
#pragma unroll
            for (int nt = 0; nt < 2; ++nt)
                bfr[nt] = *(const bf16x8*)(&Bs[wv * 32 + nt * 16 + mr][kt * 32 + qd * 8]);
#pragma unroll
            for (int mt = 0; mt < 4; ++mt)
#pragma unroll
                for (int nt = 0; nt < 2; ++nt)
                    acc[mt][nt] = __builtin_amdgcn_mfma_f32_16x16x32_bf16(
                        af[mt], bfr[nt], acc[mt][nt], 0, 0, 0);
        }
        bf16_t* out = os3[s];
#pragma unroll
        for (int mt = 0; mt < 4; ++mt)
#pragma unroll
            for (int nt = 0; nt < 2; ++nt) {
                const int col = wv * 32 + nt * 16 + mr;
                const float bb = bs3[s][col];
#pragma unroll
                for (int r = 0; r < 4; ++r) {
                    const int rowg = mbase + mt * 16 + qd * 4 + r;
                    out[(size_t)rowg * CH + col] = (bf16_t)(acc[mt][nt][r] + bb);
                }
            }
    }
}

// ---------------------------------------------------------------------------
__global__ __launch_bounds__(256)
void rowstats_k(const bf16_t* __restrict__ x1p, const bf16_t* __restrict__ x2p,
                float* __restrict__ rs)
{
    const int row = blockIdx.x * 4 + (threadIdx.x >> 6);
    const int lane = threadIdx.x & 63;
    const bf16_t* p1 = x1p + (size_t)row * CH + lane * 2;
    const bf16_t* p2 = x2p + (size_t)row * CH + lane * 2;
    float a0 = bf2f(p1[0]), a1 = bf2f(p1[1]);
    float b0 = bf2f(p2[0]), b1 = bf2f(p2[1]);
    float s = a0 + a1 + b0 + b1;
    float sq = a0 * a0 + a1 * a1 + b0 * b0 + b1 * b1;
#pragma unroll
    for (int off = 32; off > 0; off >>= 1) {
        s += __shfl_down(s, off);
        sq += __shfl_down(sq, off);
    }
    if (lane == 0) {
        float mean = s * (1.f / 256.f);
        float var = sq * (1.f / 256.f) - mean * mean;
        rs[2 * row] = mean;
        rs[2 * row + 1] = rsqrtf(var + 1e-5f);
    }
}

// ---------------------------------------------------------------------------
// MFMA window attention v2: one block per 7x7 window (2048 blocks).
// LDS 35.8 KB -> 4 blocks/CU. V preloaded to regs, staged into the score
// region after softmax. Parallel softmax (4 threads/row + shfl_xor).
// BN pass-1 partials stored per-block (no global atomic storm).
// og may alias qg (per-window partition; Q consumed before writes).
// ---------------------------------------------------------------------------
__global__ __launch_bounds__(256, 4)
void attn_k(const bf16_t* __restrict__ qg, const bf16_t* __restrict__ kg,
            const bf16_t* __restrict__ vg, bf16_t* __restrict__ og,
            float* __restrict__ partial)
{
    __shared__ __align__(16) bf16_t R0[64 * 136]; // Q -> scores f32[64][68] -> V^T bf16[128][68]
    __shared__ __align__(16) bf16_t R1[64 * 136]; // K -> P bf16[64][72]
    __shared__ float bnacc[256];
    const int tid = threadIdx.x;
    const int blk = blockIdx.x;
    const int b = blk >> 6;
    const int wy = (blk >> 3) & 7;
    const int wx = blk & 7;
    const int lane = tid & 63;
    const int wv = tid >> 6;
    const int qd = lane >> 4;
    const int mr = lane & 15;

    bnacc[tid] = 0.f;
    // ---- preload V^T chunks into registers (c-coalesced gather) ----
    uint4 vreg[4];
    const int vc = tid & 127, vhalf = tid >> 7;
#pragma unroll
    for (int jc = 0; jc < 4; ++jc) {
        bf16_t t[8];
#pragma unroll
        for (int jj = 0; jj < 8; ++jj) {
            const int j = (vhalf * 4 + jc) * 8 + jj;
            bf16_t v = (bf16_t)0.f;
            if (j < 49) {
                const int n = (wy * 7 + j / 7) * 56 + wx * 7 + (j % 7);
                v = vg[((size_t)b * N_TOK + n) * CH + vc];
            }
            t[jj] = v;
        }
        vreg[jc] = *(const uint4*)t;
    }
    // ---- stage Q,K [64 tok][128 c], rows >=49 zeroed ----
    for (int idx = tid; idx < 64 * 16; idx += 256) {
        const int i = idx >> 4, ck = idx & 15;
        uint4 uq = {0, 0, 0, 0}, uk = {0, 0, 0, 0};
        if (i < 49) {
            const int n = (wy * 7 + i / 7) * 56 + wx * 7 + (i % 7);
            const size_t off = ((size_t)b * N_TOK + n) * CH + ck * 8;
            uq = *(const uint4*)(qg + off);
            uk = *(const uint4*)(kg + off);
        }
        *(uint4*)(&R0[i * 136 + ck * 8]) = uq;
        *(uint4*)(&R1[i * 136 + ck * 8]) = uk;
    }
    __syncthreads();
    // ---- QK^T: wave wv -> q rows [wv*16,+16), 4 key tiles ----
    bf16x8 aq[4];
#pragma unroll
    for (int kt = 0; kt < 4; ++kt)
        aq[kt] = *(const bf16x8*)(&R0[(wv * 16 + mr) * 136 + kt * 32 + qd * 8]);
    f32x4 sacc[4];
#pragma unroll
    for (int nt = 0; nt < 4; ++nt) {
        f32x4 a = {0.f, 0.f, 0.f, 0.f};
#pragma unroll
        for (int kt = 0; kt < 4; ++kt) {
            bf16x8 bk = *(const bf16x8*)(&R1[(nt * 16 + mr) * 136 + kt * 32 + qd * 8]);
            a = __builtin_amdgcn_mfma_f32_16x16x32_bf16(aq[kt], bk, a, 0, 0, 0);
        }
        sacc[nt] = a;
    }
    // ---- scores -> f32 LDS [64][68] over this wave's own Q rows ----
    float* Ss = (float*)R0;
#pragma unroll
    for (int nt = 0; nt < 4; ++nt) {
        const int j = nt * 16 + mr;
#pragma unroll
        for (int r = 0; r < 4; ++r) {
            const int q = wv * 16 + qd * 4 + r;
            Ss[q * 68 + j] = (j < 49) ? sacc[nt][r] * 0.088388347648318447f : -1e30f;
        }
    }
    __syncthreads();
    // ---- parallel softmax: 4 threads per row, shfl_xor reduce ----
    {
        const int srow = tid >> 2, sq4 = tid & 3;
        const float* Sr = Ss + srow * 68 + sq4 * 16;
        float sv[16];
        *(float4*)(sv + 0)  = *(const float4*)(Sr + 0);
        *(float4*)(sv + 4)  = *(const float4*)(Sr + 4);
        *(float4*)(sv + 8)  = *(const float4*)(Sr + 8);
        *(float4*)(sv + 12) = *(const float4*)(Sr + 12);
        float mx = sv[0];
#pragma unroll
        for (int i = 1; i < 16; ++i) mx = fmaxf(mx, sv[i]);
        mx = fmaxf(mx, __shfl_xor(mx, 1));
        mx = fmaxf(mx, __shfl_xor(mx, 2));
        float sum = 0.f;
#pragma unroll
        for (int i = 0; i < 16; ++i) { sv[i] = __expf(sv[i] - mx); sum += sv[i]; }
        sum += __shfl_xor(sum, 1);
        sum += __shfl_xor(sum, 2);
        const float inv = 1.f / sum;
        __syncthreads();   // all score reads done before P overwrites R1
        uint* P32 = (uint*)R1; // P bf16 [64][72] -> uint [64][36]
#pragma unroll
        for (int i = 0; i < 8; ++i) {
            const uint lo = bfbits(sv[2 * i] * inv);
            const uint hi = bfbits(sv[2 * i + 1] * inv);
            P32[srow * 36 + sq4 * 8 + i] = lo | (hi << 16);
        }
        // ---- stage V^T bf16 [128][68] into R0 (scores dead) ----
        bf16_t* Vt = R0;
#pragma unroll
        for (int jc = 0; jc < 4; ++jc)
            *(uint4*)(&Vt[vc * 68 + (vhalf * 4 + jc) * 8]) = vreg[jc];
    }
    __syncthreads();
    // ---- PV: wave wv -> q rows [wv*16,+16) x 8 channel tiles, K=64 ----
    const bf16_t* Ps = R1;
    const bf16_t* Vt = R0;
    bf16x8 ap[2];
    ap[0] = *(const bf16x8*)(&Ps[(wv * 16 + mr) * 72 + qd * 8]);
    ap[1] = *(const bf16x8*)(&Ps[(wv * 16 + mr) * 72 + 32 + qd * 8]);
    f32x4 oacc[8];
#pragma unroll
    for (int nt = 0; nt < 8; ++nt) {
        f32x4 a = {0.f, 0.f, 0.f, 0.f};
#pragma unroll
        for (int kt = 0; kt < 2; ++kt) {
            bf16x8 bv = *(const bf16x8*)(&Vt[(nt * 16 + mr) * 68 + kt * 32 + qd * 8]);
            a = __builtin_amdgcn_mfma_f32_16x16x32_bf16(ap[kt], bv, a, 0, 0, 0);
        }
        oacc[nt] = a;
    }
    // ---- epilogue: write out + BN pass-1 partials (LDS reduce) ----
#pragma unroll
    for (int nt = 0; nt < 8; ++nt) {
        const int c = nt * 16 + mr;
        float s = 0.f, sq = 0.f;
#pragma unroll
        for (int r = 0; r < 4; ++r) {
            const int q = wv * 16 + qd * 4 + r;
            if (q < 49) {
                const float v = oacc[nt][r];
                const int n = (wy * 7 + q / 7) * 56 + wx * 7 + (q % 7);
                og[((size_t)b * N_TOK + n) * CH + c] = (bf16_t)v;
                s += v; sq += v * v;
            }
        }
        atomicAdd(&bnacc[c], s);
        atomicAdd(&bnacc[128 + c], sq);
    }
    __syncthreads();
    partial[(size_t)blk * 256 + tid] = bnacc[tid];
}

// ---------------------------------------------------------------------------
// Reduce per-block BN pass-1 partials [2048][256] into accum[0..255].
// ---------------------------------------------------------------------------
__global__ __launch_bounds__(256)
void bnreduce_k(const float* __restrict__ partial, float* __restrict__ accum)
{
    const int t = threadIdx.x;
    const int r0 = blockIdx.x * 16;
    float s = 0.f;
#pragma unroll
    for (int r = 0; r < 16; ++r) s += partial[(size_t)(r0 + r) * 256 + t];
    atomicAdd(&accum[t], s);
}

// ---------------------------------------------------------------------------
__global__ __launch_bounds__(256)
void bnstats2_k(const bf16_t* __restrict__ att, const float* __restrict__ g1,
                const float* __restrict__ b1, float* __restrict__ accum)
{
    __shared__ float ls[256], lq[256];
    const int c = threadIdx.x & 127;
    const int half = threadIdx.x >> 7;
    const float m = accum[c] * (1.f / (float)M_TOT);
    const float var = accum[128 + c] * (1.f / (float)M_TOT) - m * m;
    const float rstd = rsqrtf(var + 1e-5f);
    const float scl = g1[c] * rstd;
    const float sh = b1[c] - m * scl;
    const size_t rowbase = (size_t)blockIdx.x * 196;
    float s = 0.f, sq = 0.f;
    for (int r = half; r < 196; r += 2) {
        float z = fmaxf(0.f, bf2f(att[(rowbase + r) * CH + c]) * scl + sh);
        s += z; sq += z * z;
    }
    ls[threadIdx.x] = s; lq[threadIdx.x] = sq;
    __syncthreads();
    if (threadIdx.x < 128) {
        atomicAdd(&accum[256 + c], ls[threadIdx.x] + ls[threadIdx.x + 128]);
        atomicAdd(&accum[384 + c], lq[threadIdx.x] + lq[threadIdx.x + 128]);
    }
}

__global__ void bnparams_k(const float* __restrict__ accum,
                           const float* __restrict__ g1, const float* __restrict__ b1,
                           const float* __restrict__ g2, const float* __restrict__ b2,
                           float* __restrict__ bnp)
{
    const int c = threadIdx.x;
    const float inv = 1.f / (float)M_TOT;
    float m1 = accum[c] * inv;
    float v1 = accum[128 + c] * inv - m1 * m1;
    float rs1 = rsqrtf(v1 + 1e-5f);
    float s1 = g1[c] * rs1;
    float sh1 = b1[c] - m1 * s1;
    float m2 = accum[256 + c] * inv;
    float v2 = accum[384 + c] * inv - m2 * m2;
    float rs2 = rsqrtf(v2 + 1e-5f);
    float s2 = g2[c] * rs2;
    float sh2 = b2[c] - m2 * s2;
    bnp[c] = s1; bnp[128 + c] = sh1; bnp[256 + c] = s2; bnp[384 + c] = sh2;
}

__global__ void zero_k(float* __restrict__ p) { p[threadIdx.x] = 0.f; }

// ---------------------------------------------------------------------------
extern "C" void kernel_launch(void* const* d_in, const int* in_sizes, int n_in,
                              void* d_out, int out_size, void* d_ws, size_t ws_size,
                              hipStream_t stream)
{
    (void)in_sizes; (void)n_in; (void)out_size; (void)ws_size;
    const float* x     = (const float*)d_in[0];
    const float* fc1_w = (const float*)d_in[1];
    const float* fc1_b = (const float*)d_in[2];
    const float* fc2_w = (const float*)d_in[3];
    const float* fc2_b = (const float*)d_in[4];
    const float* fc3_w = (const float*)d_in[5];
    const float* fc3_b = (const float*)d_in[6];
    const float* fc4_w = (const float*)d_in[7];
    const float* fc4_b = (const float*)d_in[8];
    const float* fc5_w = (const float*)d_in[9];
    const float* fc5_b = (const float*)d_in[10];
    const float* fc6_w = (const float*)d_in[11];
    const float* fc6_b = (const float*)d_in[12];
    const float* ln_w  = (const float*)d_in[13];
    const float* ln_b  = (const float*)d_in[14];
    const float* q_w   = (const float*)d_in[15];
    const float* q_b   = (const float*)d_in[16];
    const float* k_w   = (const float*)d_in[17];
    const float* k_b   = (const float*)d_in[18];
    const float* v_w   = (const float*)d_in[19];
    const float* v_b   = (const float*)d_in[20];
    const float* bn1_g = (const float*)d_in[21];
    const float* bn1_b = (const float*)d_in[22];
    const float* bn2_g = (const float*)d_in[23];
    const float* bn2_b = (const float*)d_in[24];

    char* ws = (char*)d_ws;
    const size_t SZB = (size_t)M_TOT * CH * sizeof(bf16_t); // 25.7 MB
    bf16_t* bufA = (bf16_t*)(ws);            // xT -> q -> attn out
    bf16_t* bufB = (bf16_t*)(ws + SZB);      // y1T -> y3T -> x1
    bf16_t* bufC = (bf16_t*)(ws + 2 * SZB);  // x_1+x -> k
    bf16_t* bufD = (bf16_t*)(ws + 3 * SZB);  // x_2+x -> v
    float*  rs   = (float*)(ws + 4 * SZB);
    float*  accum = (float*)(ws + 4 * SZB + (size_t)M_TOT * 2 * sizeof(float));
    float*  bnp  = accum + 512;
    float*  partial = bnp + 512;             // [2048][256] BN pass-1 partials (2 MB)

    const dim3 blk(256);
    const int GG = M_TOT / 64; // 1568

    zero_k<<<1, 512, 0, stream>>>(accum);
    transpose_k<<<GG, blk, 0, stream>>>(x, bufA);
    // branch 1: fc1 (H-roll +c) + GELU -> y1T [C,N]
    gemm_k<A_FLAT, 1, E_GELU, 0, 1, 0><<<GG, blk, 0, stream>>>(
        bufA, nullptr, fc1_w, fc1_b, nullptr, nullptr, nullptr, nullptr, nullptr, bufB);
    // fc2 (W-roll +c on y1T) + x -> bufC [N,C]
    gemm_k<A_WROLL, 1, E_RES, -1, 0, 0><<<GG, blk, 0, stream>>>(
        bufB, nullptr, fc2_w, fc2_b, x, nullptr, nullptr, nullptr, nullptr, bufC);
    // branch 2: fc3 (W-roll -c) + GELU -> y3T [C,N]
    gemm_k<A_WROLL, 1, E_GELU, 1, 1, 0><<<GG, blk, 0, stream>>>(
        bufA, nullptr, fc3_w, fc3_b, nullptr, nullptr, nullptr, nullptr, nullptr, bufB);
    // fc4 (H-roll +c on y3T) + x -> bufD [N,C]
    gemm_k<A_FLAT, 1, E_RES, 0, 0, 0><<<GG, blk, 0, stream>>>(
        bufB, nullptr, fc4_w, fc4_b, x, nullptr, nullptr, nullptr, nullptr, bufD);
    // LN stats + fc5 (+x) -> bufB = x1
    rowstats_k<<<M_TOT / 4, blk, 0, stream>>>(bufC, bufD, rs);
    gemm_k<A_LN, 2, E_RES, 0, 0, 0><<<GG, blk, 0, stream>>>(
        bufC, bufD, fc5_w, fc5_b, x, rs, ln_w, ln_b, nullptr, bufB);
    // fused qkv
    qkv_k<<<GG, blk, 0, stream>>>(x, q_w, q_b, k_w, k_b, v_w, v_b, bufA, bufC, bufD);
    // MFMA window attention (+ BN pass-1 partials) -> bufA
    attn_k<<<B_SZ * 64, blk, 0, stream>>>(bufA, bufC, bufD, bufA, partial);
    bnreduce_k<<<128, blk, 0, stream>>>(partial, accum);
    // BN pass-2 stats -> params
    bnstats2_k<<<512, blk, 0, stream>>>(bufA, bn1_g, bn1_b, accum);
    bnparams_k<<<1, 128, 0, stream>>>(accum, bn1_g, bn1_b, bn2_g, bn2_b, bnp);
    // fc6 on [x1 | bn2(relu(bn1(att)))] -> d_out (f32)
    gemm_k<A_BN, 2, E_BIAS, 0, 0, 1><<<GG, blk, 0, stream>>>(
        bufB, bufA, fc6_w, fc6_b, nullptr, nullptr, nullptr, nullptr, bnp, d_out);
}

// Round 6
// 482.284 us; speedup vs baseline: 1.8625x; 1.2960x over previous
//
#include <hip/hip_runtime.h>
#include <hip/hip_bf16.h>
#include <cstdint>
#include <cstddef>

typedef __bf16 bf16_t;
typedef __bf16 bf16x8 __attribute__((ext_vector_type(8)));
typedef float f32x4 __attribute__((ext_vector_type(4)));

#define B_SZ 32
#define H_SZ 56
#define W_SZ 56
#define N_TOK 3136
#define CH 128
#define M_TOT 100352

// bf16 weight workspace offsets (elements)
#define WOFF_FC1 0
#define WOFF_FC2 16384
#define WOFF_FC3 32768
#define WOFF_FC4 49152
#define WOFF_FC5 65536
#define WOFF_FC6 98304
#define WOFF_QW  131072
#define WOFF_KW  147456
#define WOFF_VW  163840
#define WTOT     180224

enum { A_FLAT = 0, A_WROLL, A_LN, A_BN };
enum { E_BIAS = 0, E_GELU, E_RES };

__device__ __forceinline__ float bf2f(bf16_t v) { return (float)v; }
__device__ __forceinline__ unsigned short bfbits(float v) {
    bf16_t b = (bf16_t)v; unsigned short u; __builtin_memcpy(&u, &b, 2); return u;
}

// ---------------------------------------------------------------------------
// Weight pre-convert: f32 -> bf16 in B-fragment layout [n][k].
// fc weights stored [K][128] -> transposed tiles; conv weights [o][c] direct.
// 44 blocks total: 0-31 transpose tiles (64x64), 32-43 direct convert.
// ---------------------------------------------------------------------------
__global__ __launch_bounds__(256)
void wcvt_k(const float* __restrict__ f1, const float* __restrict__ f2,
            const float* __restrict__ f3, const float* __restrict__ f4,
            const float* __restrict__ f5, const float* __restrict__ f6,
            const float* __restrict__ qw, const float* __restrict__ kw,
            const float* __restrict__ vw, bf16_t* __restrict__ wb)
{
    const int blk = blockIdx.x;
    const int tid = threadIdx.x;
    if (blk < 32) {
        __shared__ bf16_t T[64][72];
        const float* src; bf16_t* dst; int K, t;
        if (blk < 4)       { src = f1; dst = wb + WOFF_FC1; K = 128; t = blk; }
        else if (blk < 8)  { src = f2; dst = wb + WOFF_FC2; K = 128; t = blk - 4; }
        else if (blk < 12) { src = f3; dst = wb + WOFF_FC3; K = 128; t = blk - 8; }
        else if (blk < 16) { src = f4; dst = wb + WOFF_FC4; K = 128; t = blk - 12; }
        else if (blk < 24) { src = f5; dst = wb + WOFF_FC5; K = 256; t = blk - 16; }
        else               { src = f6; dst = wb + WOFF_FC6; K = 256; t = blk - 24; }
        const int ti = t >> 1;          // k-tile
        const int tj = t & 1;           // n-tile
        for (int it = tid; it < 64 * 16; it += 256) {
            const int r = it >> 4, c4 = it & 15;
            float4 u = *(const float4*)(src + (size_t)(ti * 64 + r) * 128 + tj * 64 + c4 * 4);
            T[c4 * 4 + 0][r] = (bf16_t)u.x;
            T[c4 * 4 + 1][r] = (bf16_t)u.y;
            T[c4 * 4 + 2][r] = (bf16_t)u.z;
            T[c4 * 4 + 3][r] = (bf16_t)u.w;
        }
        __syncthreads();
        for (int it = tid; it < 64 * 8; it += 256) {
            const int n = it >> 3, ck = it & 7;
            *(uint4*)(dst + (size_t)(tj * 64 + n) * K + ti * 64 + ck * 8) =
                *(const uint4*)(&T[n][ck * 8]);
        }
    } else {
        const float* src; bf16_t* dst;
        int t = blk - 32;
        if (t < 4)      { src = qw; dst = wb + WOFF_QW; }
        else if (t < 8) { src = kw; dst = wb + WOFF_KW; t -= 4; }
        else            { src = vw; dst = wb + WOFF_VW; t -= 8; }
        const int base = t * 4096 + tid * 16;
        float4 u0 = *(const float4*)(src + base);
        float4 u1 = *(const float4*)(src + base + 4);
        float4 u2 = *(const float4*)(src + base + 8);
        float4 u3 = *(const float4*)(src + base + 12);
        bf16_t o[16] = {(bf16_t)u0.x, (bf16_t)u0.y, (bf16_t)u0.z, (bf16_t)u0.w,
                        (bf16_t)u1.x, (bf16_t)u1.y, (bf16_t)u1.z, (bf16_t)u1.w,
                        (bf16_t)u2.x, (bf16_t)u2.y, (bf16_t)u2.z, (bf16_t)u2.w,
                        (bf16_t)u3.x, (bf16_t)u3.y, (bf16_t)u3.z, (bf16_t)u3.w};
        *(uint4*)(dst + base) = *(const uint4*)o;
        *(uint4*)(dst + base + 8) = *(const uint4*)(o + 8);
    }
}

// ---------------------------------------------------------------------------
// Transpose: x[B,N,C] f32 -> xT[B,C,N] bf16. 64 tokens per block.
// ---------------------------------------------------------------------------
__global__ __launch_bounds__(256)
void transpose_k(const float* __restrict__ x, bf16_t* __restrict__ xT)
{
    __shared__ bf16_t T[128][70];
    const int tid = threadIdx.x;
    const int mbase = blockIdx.x * 64;
    const int bimg = mbase / N_TOK;
    const int n0 = mbase - bimg * N_TOK;
    for (int idx = tid; idx < 64 * 32; idx += 256) {
        const int tok = idx >> 5, cg = idx & 31;
        float4 u = *(const float4*)(x + (size_t)(mbase + tok) * CH + cg * 4);
        T[cg * 4 + 0][tok] = (bf16_t)u.x;
        T[cg * 4 + 1][tok] = (bf16_t)u.y;
        T[cg * 4 + 2][tok] = (bf16_t)u.z;
        T[cg * 4 + 3][tok] = (bf16_t)u.w;
    }
    __syncthreads();
    const uint* T32 = (const uint*)&T[0][0]; // [128][35]
    for (int idx = tid; idx < 128 * 8; idx += 256) {
        const int c = idx >> 3, chunk = idx & 7;
        uint4 o;
        o.x = T32[c * 35 + chunk * 4 + 0];
        o.y = T32[c * 35 + chunk * 4 + 1];
        o.z = T32[c * 35 + chunk * 4 + 2];
        o.w = T32[c * 35 + chunk * 4 + 3];
        *(uint4*)(xT + ((size_t)(bimg * 128 + c)) * N_TOK + n0 + chunk * 8) = o;
    }
}

// ---------------------------------------------------------------------------
// MFMA GEMM: out[M,128] = f(A) @ W + bias (+epilogue). 64x128 tile.
// B fragments read DIRECTLY from preconverted bf16 global weights [n][K]
// (L1/L2-hot) -- no B LDS staging. LDS = 17.9 KB (A tile + OTRANS scratch).
// ---------------------------------------------------------------------------
template<int AMODE, int KHALVES, int EPI, int WDIR, int OTRANS, int OF32>
__global__ __launch_bounds__(256)
void gemm_k(const bf16_t* __restrict__ A0, const bf16_t* __restrict__ A1,
            const bf16_t* __restrict__ Wt, const float* __restrict__ bias,
            const float* __restrict__ resid,
            const float* __restrict__ rowst,
            const float* __restrict__ lnw, const float* __restrict__ lnb,
            const float* __restrict__ bnp,
            void* __restrict__ outv)
{
    __shared__ __align__(16) char smem[17920]; // As [64][136] bf16 / T32 [128][35] uint
    bf16_t* As = (bf16_t*)smem;
    const int tid = threadIdx.x;
    const int mbase = blockIdx.x * 64;
    const int bimg = mbase / N_TOK;
    const int n0 = mbase - bimg * N_TOK;
    const int lane = tid & 63;
    const int wv = tid >> 6;
    const int qd = lane >> 4;
    const int mr = lane & 15;
    const int KS = 128 * KHALVES;

    f32x4 acc[4][2];
#pragma unroll
    for (int i = 0; i < 4; ++i)
#pragma unroll
        for (int j = 0; j < 2; ++j) { f32x4 z = {0.f,0.f,0.f,0.f}; acc[i][j] = z; }

    for (int kh = 0; kh < KHALVES; ++kh) {
        if (kh) __syncthreads();
        // ---- stage A tile [64 tok][128 k] ----
        if (AMODE == A_FLAT || AMODE == A_WROLL) {
            for (int idx = tid; idx < 128 * 8; idx += 256) {
                const int c = idx >> 3, chunk = idx & 7;
                const int cm = (c >= 112) ? c - 112 : (c >= 56 ? c - 56 : c);
                const bf16_t* crow = A0 + ((size_t)(bimg * 128 + c)) * N_TOK;
                if (AMODE == A_FLAT) {
                    int t = n0 + chunk * 8 + N_TOK - 56 * cm;
                    if (t >= N_TOK) t -= N_TOK;
                    uint4 u = *(const uint4*)(crow + t);
                    const bf16_t* up = (const bf16_t*)&u;
#pragma unroll
                    for (int j = 0; j < 8; ++j) As[(chunk * 8 + j) * 136 + c] = up[j];
                } else {
                    const int nl = n0 + chunk * 8;
                    const int h = nl / 56;
                    const int w0 = nl - h * 56;
                    int ws = (WDIR > 0) ? (w0 + cm) : (w0 + 56 - cm);
                    if (ws >= 56) ws -= 56;
                    const bf16_t* hrow = crow + h * 56;
                    if (ws <= 48) {
                        uint4 u = *(const uint4*)(hrow + ws);
                        const bf16_t* up = (const bf16_t*)&u;
#pragma unroll
                        for (int j = 0; j < 8; ++j) As[(chunk * 8 + j) * 136 + c] = up[j];
                    } else {
#pragma unroll
                        for (int j = 0; j < 8; ++j) {
                            int wj = ws + j; if (wj >= 56) wj -= 56;
                            As[(chunk * 8 + j) * 136 + c] = hrow[wj];
                        }
                    }
                }
            }
        } else if (AMODE == A_LN) {
            for (int idx = tid; idx < 64 * 16; idx += 256) {
                const int row = idx >> 4, ck = idx & 15;
                const int rowg = mbase + row;
                const bf16_t* src = kh ? A1 : A0;
                uint4 u = *(const uint4*)(src + (size_t)rowg * CH + ck * 8);
                const bf16_t* up = (const bf16_t*)&u;
                const float mean = rowst[2 * rowg];
                const float rstd = rowst[2 * rowg + 1];
                const int cabs = kh * 128 + ck * 8;
                bf16_t t[8];
#pragma unroll
                for (int j = 0; j < 8; ++j) {
                    float v = (bf2f(up[j]) - mean) * rstd;
                    v = v * lnw[cabs + j] + lnb[cabs + j];
                    t[j] = (bf16_t)v;
                }
                *(uint4*)(&As[row * 136 + ck * 8]) = *(const uint4*)t;
            }
        } else { // A_BN
            for (int idx = tid; idx < 64 * 16; idx += 256) {
                const int row = idx >> 4, ck = idx & 15;
                const int rowg = mbase + row;
                if (kh == 0) {
                    uint4 u = *(const uint4*)(A0 + (size_t)rowg * CH + ck * 8);
                    *(uint4*)(&As[row * 136 + ck * 8]) = u;
                } else {
                    uint4 u = *(const uint4*)(A1 + (size_t)rowg * CH + ck * 8);
                    const bf16_t* up = (const bf16_t*)&u;
                    bf16_t t[8];
#pragma unroll
                    for (int j = 0; j < 8; ++j) {
                        const int c = ck * 8 + j;
                        float z = fmaxf(0.f, bf2f(up[j]) * bnp[c] + bnp[128 + c]);
                        t[j] = (bf16_t)(z * bnp[256 + c] + bnp[384 + c]);
                    }
                    *(uint4*)(&As[row * 136 + ck * 8]) = *(const uint4*)t;
                }
            }
        }
        __syncthreads();
        // ---- MFMA: B fragments straight from global (L1-hot weights) ----
        const bf16_t* wbase = Wt + (size_t)(wv * 32 + mr) * KS + kh * 128 + qd * 8;
#pragma unroll
        for (int kt = 0; kt < 4; ++kt) {
            bf16x8 af[4], bfr[2];
#pragma unroll
            for (int mt = 0; mt < 4; ++mt)
                af[mt] = *(const bf16x8*)(&As[(mt * 16 + mr) * 136 + kt * 32 + qd * 8]);
#pragma unroll
            for (int nt = 0; nt < 2; ++nt)
                bfr[nt] = *(const bf16x8*)(wbase + (size_t)(nt * 16) * KS + kt * 32);
#pragma unroll
            for (int mt = 0; mt < 4; ++mt)
#pragma unroll
                for (int nt = 0; nt < 2; ++nt)
                    acc[mt][nt] = __builtin_amdgcn_mfma_f32_16x16x32_bf16(
                        af[mt], bfr[nt], acc[mt][nt], 0, 0, 0);
        }
    }
    // ---- epilogue ----
    if (OTRANS) {
        __syncthreads();               // As reads complete
        uint* T32 = (uint*)smem;       // [128][35]
#pragma unroll
        for (int mt = 0; mt < 4; ++mt)
#pragma unroll
            for (int nt = 0; nt < 2; ++nt) {
                const int col = wv * 32 + nt * 16 + mr;
                const float bb = bias[col];
#pragma unroll
                for (int rp = 0; rp < 2; ++rp) {
                    float v0 = acc[mt][nt][2 * rp] + bb;
                    float v1 = acc[mt][nt][2 * rp + 1] + bb;
                    if (EPI == E_GELU) {
                        v0 = 0.5f * v0 * (1.f + erff(v0 * 0.70710678118654752f));
                        v1 = 0.5f * v1 * (1.f + erff(v1 * 0.70710678118654752f));
                    }
                    T32[col * 35 + mt * 8 + qd * 2 + rp] =
                        (uint)bfbits(v0) | ((uint)bfbits(v1) << 16);
                }
            }
        __syncthreads();
        const int c = tid >> 1, half = tid & 1;
        uint r[16];
#pragma unroll
        for (int j = 0; j < 16; ++j) r[j] = T32[c * 35 + half * 16 + j];
        bf16_t* op = (bf16_t*)outv + ((size_t)(bimg * 128 + c)) * N_TOK + n0 + half * 32;
        uint4 o0 = {r[0], r[1], r[2], r[3]};
        uint4 o1 = {r[4], r[5], r[6], r[7]};
        uint4 o2 = {r[8], r[9], r[10], r[11]};
        uint4 o3 = {r[12], r[13], r[14], r[15]};
        ((uint4*)op)[0] = o0; ((uint4*)op)[1] = o1;
        ((uint4*)op)[2] = o2; ((uint4*)op)[3] = o3;
    } else {
#pragma unroll
        for (int mt = 0; mt < 4; ++mt)
#pragma unroll
            for (int nt = 0; nt < 2; ++nt) {
                const int col = wv * 32 + nt * 16 + mr;
                const float bb = bias[col];
#pragma unroll
                for (int r = 0; r < 4; ++r) {
                    const int rowg = mbase + mt * 16 + qd * 4 + r;
                    float v = acc[mt][nt][r] + bb;
                    if (EPI == E_GELU) v = 0.5f * v * (1.f + erff(v * 0.70710678118654752f));
                    if (EPI == E_RES)  v += resid[(size_t)rowg * CH + col];
                    if (OF32) ((float*)outv)[(size_t)rowg * CH + col] = v;
                    else ((bf16_t*)outv)[(size_t)rowg * CH + col] = (bf16_t)v;
                }
            }
    }
}

// ---------------------------------------------------------------------------
// Fused q/k/v: stage x-tile once (17.4 KB LDS); weights direct from global.
// ---------------------------------------------------------------------------
__global__ __launch_bounds__(256)
void qkv_k(const float* __restrict__ x, const bf16_t* __restrict__ wb,
           const float* __restrict__ qb, const float* __restrict__ kb,
           const float* __restrict__ vb,
           bf16_t* __restrict__ qo, bf16_t* __restrict__ ko, bf16_t* __restrict__ vo)
{
    __shared__ __align__(16) bf16_t As[64 * 136];
    const int tid = threadIdx.x;
    const int mbase = blockIdx.x * 64;
    const int lane = tid & 63;
    const int wv = tid >> 6;
    const int qd = lane >> 4;
    const int mr = lane & 15;

    for (int idx = tid; idx < 64 * 16; idx += 256) {
        const int row = idx >> 4, ck = idx & 15;
        const float* p = x + (size_t)(mbase + row) * CH + ck * 8;
        float4 u0 = *(const float4*)p;
        float4 u1 = *(const float4*)(p + 4);
        bf16_t t[8] = {(bf16_t)u0.x, (bf16_t)u0.y, (bf16_t)u0.z, (bf16_t)u0.w,
                       (bf16_t)u1.x, (bf16_t)u1.y, (bf16_t)u1.z, (bf16_t)u1.w};
        *(uint4*)(&As[row * 136 + ck * 8]) = *(const uint4*)t;
    }
    __syncthreads();
    bf16x8 af[4][4];
#pragma unroll
    for (int kt = 0; kt < 4; ++kt)
#pragma unroll
        for (int mt = 0; mt < 4; ++mt)
            af[kt][mt] = *(const bf16x8*)(&As[(mt * 16 + mr) * 136 + kt * 32 + qd * 8]);

    const int woffs[3] = {WOFF_QW, WOFF_KW, WOFF_VW};
    const float* bs3[3] = {qb, kb, vb};
    bf16_t* os3[3] = {qo, ko, vo};
#pragma unroll
    for (int s = 0; s < 3; ++s) {
        const bf16_t* wbase = wb + woffs[s] + (size_t)(wv * 32 + mr) * 128 + qd * 8;
        f32x4 acc[4][2];
#pragma unroll
        for (int i = 0; i < 4; ++i)
#pragma unroll
            for (int j = 0; j < 2; ++j) { f32x4 z = {0.f,0.f,0.f,0.f}; acc[i][j] = z; }
#pragma unroll
        for (int kt = 0; kt < 4; ++kt) {
            bf16x8 bfr[2];
#pragma unroll
            for (int nt = 0; nt < 2; ++nt)
                bfr[nt] = *(const bf16x8*)(wbase + (nt * 16) * 128 + kt * 32);
#pragma unroll
            for (int mt = 0; mt < 4; ++mt)
#pragma unroll
                for (int nt = 0; nt < 2; ++nt)
                    acc[mt][nt] = __builtin_amdgcn_mfma_f32_16x16x32_bf16(
                        af[kt][mt], bfr[nt], acc[mt][nt], 0, 0, 0);
        }
        bf16_t* out = os3[s];
#pragma unroll
        for (int mt = 0; mt < 4; ++mt)
#pragma unroll
            for (int nt = 0; nt < 2; ++nt) {
                const int col = wv * 32 + nt * 16 + mr;
                const float bb = bs3[s][col];
#pragma unroll
                for (int r = 0; r < 4; ++r) {
                    const int rowg = mbase + mt * 16 + qd * 4 + r;
                    out[(size_t)rowg * CH + col] = (bf16_t)(acc[mt][nt][r] + bb);
                }
            }
    }
}

// ---------------------------------------------------------------------------
__global__ __launch_bounds__(256)
void rowstats_k(const bf16_t* __restrict__ x1p, const bf16_t* __restrict__ x2p,
                float* __restrict__ rs)
{
    const int row = blockIdx.x * 4 + (threadIdx.x >> 6);
    const int lane = threadIdx.x & 63;
    const bf16_t* p1 = x1p + (size_t)row * CH + lane * 2;
    const bf16_t* p2 = x2p + (size_t)row * CH + lane * 2;
    float a0 = bf2f(p1[0]), a1 = bf2f(p1[1]);
    float b0 = bf2f(p2[0]), b1 = bf2f(p2[1]);
    float s = a0 + a1 + b0 + b1;
    float sq = a0 * a0 + a1 * a1 + b0 * b0 + b1 * b1;
#pragma unroll
    for (int off = 32; off > 0; off >>= 1) {
        s += __shfl_down(s, off);
        sq += __shfl_down(sq, off);
    }
    if (lane == 0) {
        float mean = s * (1.f / 256.f);
        float var = sq * (1.f / 256.f) - mean * mean;
        rs[2 * row] = mean;
        rs[2 * row + 1] = rsqrtf(var + 1e-5f);
    }
}

// ---------------------------------------------------------------------------
// MFMA window attention (as R5): one block per 7x7 window.
// ---------------------------------------------------------------------------
__global__ __launch_bounds__(256, 4)
void attn_k(const bf16_t* __restrict__ qg, const bf16_t* __restrict__ kg,
            const bf16_t* __restrict__ vg, bf16_t* __restrict__ og,
            float* __restrict__ partial)
{
    __shared__ __align__(16) bf16_t R0[64 * 136]; // Q -> scores f32[64][68] -> V^T bf16[128][68]
    __shared__ __align__(16) bf16_t R1[64 * 136]; // K -> P bf16[64][72]
    __shared__ float bnacc[256];
    const int tid = threadIdx.x;
    const int blk = blockIdx.x;
    const int b = blk >> 6;
    const int wy = (blk >> 3) & 7;
    const int wx = blk & 7;
    const int lane = tid & 63;
    const int wv = tid >> 6;
    const int qd = lane >> 4;
    const int mr = lane & 15;

    bnacc[tid] = 0.f;
    uint4 vreg[4];
    const int vc = tid & 127, vhalf = tid >> 7;
#pragma unroll
    for (int jc = 0; jc < 4; ++jc) {
        bf16_t t[8];
#pragma unroll
        for (int jj = 0; jj < 8; ++jj) {
            const int j = (vhalf * 4 + jc) * 8 + jj;
            bf16_t v = (bf16_t)0.f;
            if (j < 49) {
                const int n = (wy * 7 + j / 7) * 56 + wx * 7 + (j % 7);
                v = vg[((size_t)b * N_TOK + n) * CH + vc];
            }
            t[jj] = v;
        }
        vreg[jc] = *(const uint4*)t;
    }
    for (int idx = tid; idx < 64 * 16; idx += 256) {
        const int i = idx >> 4, ck = idx & 15;
        uint4 uq = {0, 0, 0, 0}, uk = {0, 0, 0, 0};
        if (i < 49) {
            const int n = (wy * 7 + i / 7) * 56 + wx * 7 + (i % 7);
            const size_t off = ((size_t)b * N_TOK + n) * CH + ck * 8;
            uq = *(const uint4*)(qg + off);
            uk = *(const uint4*)(kg + off);
        }
        *(uint4*)(&R0[i * 136 + ck * 8]) = uq;
        *(uint4*)(&R1[i * 136 + ck * 8]) = uk;
    }
    __syncthreads();
    bf16x8 aq[4];
#pragma unroll
    for (int kt = 0; kt < 4; ++kt)
        aq[kt] = *(const bf16x8*)(&R0[(wv * 16 + mr) * 136 + kt * 32 + qd * 8]);
    f32x4 sacc[4];
#pragma unroll
    for (int nt = 0; nt < 4; ++nt) {
        f32x4 a = {0.f, 0.f, 0.f, 0.f};
#pragma unroll
        for (int kt = 0; kt < 4; ++kt) {
            bf16x8 bk = *(const bf16x8*)(&R1[(nt * 16 + mr) * 136 + kt * 32 + qd * 8]);
            a = __builtin_amdgcn_mfma_f32_16x16x32_bf16(aq[kt], bk, a, 0, 0, 0);
        }
        sacc[nt] = a;
    }
    float* Ss = (float*)R0;
#pragma unroll
    for (int nt = 0; nt < 4; ++nt) {
        const int j = nt * 16 + mr;
#pragma unroll
        for (int r = 0; r < 4; ++r) {
            const int q = wv * 16 + qd * 4 + r;
            Ss[q * 68 + j] = (j < 49) ? sacc[nt][r] * 0.088388347648318447f : -1e30f;
        }
    }
    __syncthreads();
    {
        const int srow = tid >> 2, sq4 = tid & 3;
        const float* Sr = Ss + srow * 68 + sq4 * 16;
        float sv[16];
        *(float4*)(sv + 0)  = *(const float4*)(Sr + 0);
        *(float4*)(sv + 4)  = *(const float4*)(Sr + 4);
        *(float4*)(sv + 8)  = *(const float4*)(Sr + 8);
        *(float4*)(sv + 12) = *(const float4*)(Sr + 12);
        float mx = sv[0];
#pragma unroll
        for (int i = 1; i < 16; ++i) mx = fmaxf(mx, sv[i]);
        mx = fmaxf(mx, __shfl_xor(mx, 1));
        mx = fmaxf(mx, __shfl_xor(mx, 2));
        float sum = 0.f;
#pragma unroll
        for (int i = 0; i < 16; ++i) { sv[i] = __expf(sv[i] - mx); sum += sv[i]; }
        sum += __shfl_xor(sum, 1);
        sum += __shfl_xor(sum, 2);
        const float inv = 1.f / sum;
        __syncthreads();
        uint* P32 = (uint*)R1;
#pragma unroll
        for (int i = 0; i < 8; ++i) {
            const uint lo = bfbits(sv[2 * i] * inv);
            const uint hi = bfbits(sv[2 * i + 1] * inv);
            P32[srow * 36 + sq4 * 8 + i] = lo | (hi << 16);
        }
        bf16_t* Vt = R0;
#pragma unroll
        for (int jc = 0; jc < 4; ++jc)
            *(uint4*)(&Vt[vc * 68 + (vhalf * 4 + jc) * 8]) = vreg[jc];
    }
    __syncthreads();
    const bf16_t* Ps = R1;
    const bf16_t* Vt = R0;
    bf16x8 ap[2];
    ap[0] = *(const bf16x8*)(&Ps[(wv * 16 + mr) * 72 + qd * 8]);
    ap[1] = *(const bf16x8*)(&Ps[(wv * 16 + mr) * 72 + 32 + qd * 8]);
    f32x4 oacc[8];
#pragma unroll
    for (int nt = 0; nt < 8; ++nt) {
        f32x4 a = {0.f, 0.f, 0.f, 0.f};
#pragma unroll
        for (int kt = 0; kt < 2; ++kt) {
            bf16x8 bv = *(const bf16x8*)(&Vt[(nt * 16 + mr) * 68 + kt * 32 + qd * 8]);
            a = __builtin_amdgcn_mfma_f32_16x16x32_bf16(ap[kt], bv, a, 0, 0, 0);
        }
        oacc[nt] = a;
    }
#pragma unroll
    for (int nt = 0; nt < 8; ++nt) {
        const int c = nt * 16 + mr;
        float s = 0.f, sq = 0.f;
#pragma unroll
        for (int r = 0; r < 4; ++r) {
            const int q = wv * 16 + qd * 4 + r;
            if (q < 49) {
                const float v = oacc[nt][r];
                const int n = (wy * 7 + q / 7) * 56 + wx * 7 + (q % 7);
                og[((size_t)b * N_TOK + n) * CH + c] = (bf16_t)v;
                s += v; sq += v * v;
            }
        }
        atomicAdd(&bnacc[c], s);
        atomicAdd(&bnacc[128 + c], sq);
    }
    __syncthreads();
    partial[(size_t)blk * 256 + tid] = bnacc[tid];
}

// ---------------------------------------------------------------------------
__global__ __launch_bounds__(256)
void bnreduce_k(const float* __restrict__ partial, float* __restrict__ accum)
{
    const int t = threadIdx.x;
    const int r0 = blockIdx.x * 16;
    float s = 0.f;
#pragma unroll
    for (int r = 0; r < 16; ++r) s += partial[(size_t)(r0 + r) * 256 + t];
    atomicAdd(&accum[t], s);
}

__global__ __launch_bounds__(256)
void bnstats2_k(const bf16_t* __restrict__ att, const float* __restrict__ g1,
                const float* __restrict__ b1, float* __restrict__ accum)
{
    __shared__ float ls[256], lq[256];
    const int c = threadIdx.x & 127;
    const int half = threadIdx.x >> 7;
    const float m = accum[c] * (1.f / (float)M_TOT);
    const float var = accum[128 + c] * (1.f / (float)M_TOT) - m * m;
    const float rstd = rsqrtf(var + 1e-5f);
    const float scl = g1[c] * rstd;
    const float sh = b1[c] - m * scl;
    const size_t rowbase = (size_t)blockIdx.x * 196;
    float s = 0.f, sq = 0.f;
    for (int r = half; r < 196; r += 2) {
        float z = fmaxf(0.f, bf2f(att[(rowbase + r) * CH + c]) * scl + sh);
        s += z; sq += z * z;
    }
    ls[threadIdx.x] = s; lq[threadIdx.x] = sq;
    __syncthreads();
    if (threadIdx.x < 128) {
        atomicAdd(&accum[256 + c], ls[threadIdx.x] + ls[threadIdx.x + 128]);
        atomicAdd(&accum[384 + c], lq[threadIdx.x] + lq[threadIdx.x + 128]);
    }
}

__global__ void bnparams_k(const float* __restrict__ accum,
                           const float* __restrict__ g1, const float* __restrict__ b1,
                           const float* __restrict__ g2, const float* __restrict__ b2,
                           float* __restrict__ bnp)
{
    const int c = threadIdx.x;
    const float inv = 1.f / (float)M_TOT;
    float m1 = accum[c] * inv;
    float v1 = accum[128 + c] * inv - m1 * m1;
    float rs1 = rsqrtf(v1 + 1e-5f);
    float s1 = g1[c] * rs1;
    float sh1 = b1[c] - m1 * s1;
    float m2 = accum[256 + c] * inv;
    float v2 = accum[384 + c] * inv - m2 * m2;
    float rs2 = rsqrtf(v2 + 1e-5f);
    float s2 = g2[c] * rs2;
    float sh2 = b2[c] - m2 * s2;
    bnp[c] = s1; bnp[128 + c] = sh1; bnp[256 + c] = s2; bnp[384 + c] = sh2;
}

__global__ void zero_k(float* __restrict__ p) { p[threadIdx.x] = 0.f; }

// ---------------------------------------------------------------------------
extern "C" void kernel_launch(void* const* d_in, const int* in_sizes, int n_in,
                              void* d_out, int out_size, void* d_ws, size_t ws_size,
                              hipStream_t stream)
{
    (void)in_sizes; (void)n_in; (void)out_size; (void)ws_size;
    const float* x     = (const float*)d_in[0];
    const float* fc1_w = (const float*)d_in[1];
    const float* fc1_b = (const float*)d_in[2];
    const float* fc2_w = (const float*)d_in[3];
    const float* fc2_b = (const float*)d_in[4];
    const float* fc3_w = (const float*)d_in[5];
    const float* fc3_b = (const float*)d_in[6];
    const float* fc4_w = (const float*)d_in[7];
    const float* fc4_b = (const float*)d_in[8];
    const float* fc5_w = (const float*)d_in[9];
    const float* fc5_b = (const float*)d_in[10];
    const float* fc6_w = (const float*)d_in[11];
    const float* fc6_b = (const float*)d_in[12];
    const float* ln_w  = (const float*)d_in[13];
    const float* ln_b  = (const float*)d_in[14];
    const float* q_w   = (const float*)d_in[15];
    const float* q_b   = (const float*)d_in[16];
    const float* k_w   = (const float*)d_in[17];
    const float* k_b   = (const float*)d_in[18];
    const float* v_w   = (const float*)d_in[19];
    const float* v_b   = (const float*)d_in[20];
    const float* bn1_g = (const float*)d_in[21];
    const float* bn1_b = (const float*)d_in[22];
    const float* bn2_g = (const float*)d_in[23];
    const float* bn2_b = (const float*)d_in[24];

    char* ws = (char*)d_ws;
    const size_t SZB = (size_t)M_TOT * CH * sizeof(bf16_t); // 25.7 MB
    bf16_t* bufA = (bf16_t*)(ws);            // xT -> q -> attn out
    bf16_t* bufB = (bf16_t*)(ws + SZB);      // y1T -> y3T -> x1
    bf16_t* bufC = (bf16_t*)(ws + 2 * SZB);  // x_1+x -> k
    bf16_t* bufD = (bf16_t*)(ws + 3 * SZB);  // x_2+x -> v
    float*  rs   = (float*)(ws + 4 * SZB);
    float*  accum = (float*)(ws + 4 * SZB + (size_t)M_TOT * 2 * sizeof(float));
    float*  bnp  = accum + 512;
    float*  partial = bnp + 512;             // [2048][256] (2 MB)
    bf16_t* wbuf = (bf16_t*)(partial + 2048 * 256); // preconverted weights (0.36 MB)

    const dim3 blk(256);
    const int GG = M_TOT / 64; // 1568

    zero_k<<<1, 512, 0, stream>>>(accum);
    wcvt_k<<<44, blk, 0, stream>>>(fc1_w, fc2_w, fc3_w, fc4_w, fc5_w, fc6_w,
                                   q_w, k_w, v_w, wbuf);
    transpose_k<<<GG, blk, 0, stream>>>(x, bufA);
    // branch 1: fc1 (H-roll +c) + GELU -> y1T [C,N]
    gemm_k<A_FLAT, 1, E_GELU, 0, 1, 0><<<GG, blk, 0, stream>>>(
        bufA, nullptr, wbuf + WOFF_FC1, fc1_b, nullptr, nullptr, nullptr, nullptr, nullptr, bufB);
    // fc2 (W-roll +c on y1T) + x -> bufC [N,C]
    gemm_k<A_WROLL, 1, E_RES, -1, 0, 0><<<GG, blk, 0, stream>>>(
        bufB, nullptr, wbuf + WOFF_FC2, fc2_b, x, nullptr, nullptr, nullptr, nullptr, bufC);
    // branch 2: fc3 (W-roll -c) + GELU -> y3T [C,N]
    gemm_k<A_WROLL, 1, E_GELU, 1, 1, 0><<<GG, blk, 0, stream>>>(
        bufA, nullptr, wbuf + WOFF_FC3, fc3_b, nullptr, nullptr, nullptr, nullptr, nullptr, bufB);
    // fc4 (H-roll +c on y3T) + x -> bufD [N,C]
    gemm_k<A_FLAT, 1, E_RES, 0, 0, 0><<<GG, blk, 0, stream>>>(
        bufB, nullptr, wbuf + WOFF_FC4, fc4_b, x, nullptr, nullptr, nullptr, nullptr, bufD);
    // LN stats + fc5 (+x) -> bufB = x1
    rowstats_k<<<M_TOT / 4, blk, 0, stream>>>(bufC, bufD, rs);
    gemm_k<A_LN, 2, E_RES, 0, 0, 0><<<GG, blk, 0, stream>>>(
        bufC, bufD, wbuf + WOFF_FC5, fc5_b, x, rs, ln_w, ln_b, nullptr, bufB);
    // fused qkv
    qkv_k<<<GG, blk, 0, stream>>>(x, wbuf, q_b, k_b, v_b, bufA, bufC, bufD);
    // MFMA window attention (+ BN pass-1 partials) -> bufA
    attn_k<<<B_SZ * 64, blk, 0, stream>>>(bufA, bufC, bufD, bufA, partial);
    bnreduce_k<<<128, blk, 0, stream>>>(partial, accum);
    bnstats2_k<<<512, blk, 0, stream>>>(bufA, bn1_g, bn1_b, accum);
    bnparams_k<<<1, 128, 0, stream>>>(accum, bn1_g, bn1_b, bn2_g, bn2_b, bnp);
    // fc6 on [x1 | bn2(relu(bn1(att)))] -> d_out (f32)
    gemm_k<A_BN, 2, E_BIAS, 0, 0, 1><<<GG, blk, 0, stream>>>(
        bufB, bufA, wbuf + WOFF_FC6, fc6_b, nullptr, nullptr, nullptr, nullptr, bnp, d_out);
}